// Round 15
// baseline (185.293 us; speedup 1.0000x reference)
//
#include <hip/hip_runtime.h>
#include <hip/hip_bf16.h>

#define B_ 4
#define S_ 2048
#define D_ 768
#define H_ 12
#define HD_ 64
#define M_ (B_*S_)   // 8192
#define LOG2E 1.44269504088896f

typedef __attribute__((ext_vector_type(8))) short bf8;
typedef __attribute__((ext_vector_type(4))) float f4;
typedef unsigned short u16;
typedef unsigned int   u32;

__device__ __forceinline__ float bf2f(u16 u) {
  union { u32 i; float f; } c; c.i = ((u32)u) << 16; return c.f;
}
__device__ __forceinline__ u16 f2bf(float x) {
  union { float f; u32 i; } c; c.f = x;
  u32 r = (c.i + 0x7FFFu + ((c.i >> 16) & 1u)) >> 16;
  return (u16)r;
}
// single-instruction RNE f32->bf16 (low half of v_cvt_pk result)
__device__ __forceinline__ u16 cvt_bf16(float x) {
  u32 r;
  asm("v_cvt_pk_bf16_f32 %0, %1, %1" : "=v"(r) : "v"(x));
  return (u16)r;
}

// f32 -> bf16 (rne), vectorized x4, grid-stride.
__global__ __launch_bounds__(256) void stage_cvt(const float* __restrict__ in,
                                                 u16* __restrict__ out, int n4)
{
  for (int i = blockIdx.x * blockDim.x + threadIdx.x; i < n4; i += gridDim.x * blockDim.x) {
    float4 v = ((const float4*)in)[i];
    ushort4 o;
    o.x = f2bf(v.x); o.y = f2bf(v.y); o.z = f2bf(v.z); o.w = f2bf(v.w);
    ((ushort4*)out)[i] = o;
  }
}

// 4 weight matrices in one launch (blockIdx.y selects).
__global__ __launch_bounds__(256) void stage_w4(const float* __restrict__ w0, const float* __restrict__ w1,
                                                const float* __restrict__ w2, const float* __restrict__ w3,
                                                u16* __restrict__ o0, u16* __restrict__ o1,
                                                u16* __restrict__ o2, u16* __restrict__ o3, int n4)
{
  const float* src = (blockIdx.y == 0) ? w0 : (blockIdx.y == 1) ? w1 : (blockIdx.y == 2) ? w2 : w3;
  u16*         dst = (blockIdx.y == 0) ? o0 : (blockIdx.y == 1) ? o1 : (blockIdx.y == 2) ? o2 : o3;
  for (int i = blockIdx.x * blockDim.x + threadIdx.x; i < n4; i += gridDim.x * blockDim.x) {
    float4 v = ((const float4*)src)[i];
    ushort4 o;
    o.x = f2bf(v.x); o.y = f2bf(v.y); o.z = f2bf(v.z); o.w = f2bf(v.w);
    ((ushort4*)dst)[i] = o;
  }
}

__device__ __forceinline__ bf8 ldcvt8(const float* __restrict__ p) {
  float4 a = *(const float4*)p;
  float4 b = *(const float4*)(p + 4);
  bf8 r;
  r[0] = f2bf(a.x); r[1] = f2bf(a.y); r[2] = f2bf(a.z); r[3] = f2bf(a.w);
  r[4] = f2bf(b.x); r[5] = f2bf(b.y); r[6] = f2bf(b.z); r[7] = f2bf(b.w);
  return r;
}

#define MFMA_BF16 __builtin_amdgcn_mfma_f32_16x16x32_bf16

// GEMM v2: LDS-staged + T14 reg prefetch, tile 64x128, BK=64.
// EPI: 0 = bf16 store; 1 = head-L2-normalize; 2 = normalize*temp[h]*log2e (Q path);
//      3 = f32 store.
template <int EPI>
__global__ __launch_bounds__(256) void gemm_v2(const u16* __restrict__ A,
                                               const u16* __restrict__ W,
                                               u16* __restrict__ Cb,
                                               float* __restrict__ Cf,
                                               const float* __restrict__ temp)
{
  const int w  = threadIdx.x >> 6;
  const int ln = threadIdx.x & 63;
  const int li = ln & 15, g = ln >> 4;
  const int wr = w >> 1, wc = w & 1;
  const int row0 = blockIdx.x * 64;
  const int col0 = blockIdx.y * 128;

  __shared__ __align__(16) u16 a_lds[64][72];
  __shared__ __align__(16) u16 b_lds[128][72];

  const int rowA = threadIdx.x >> 2;
  const int cA   = (threadIdx.x & 3) * 8;
  const int rowB = threadIdx.x >> 1;
  const int cB   = (threadIdx.x & 1) * 32;

  const u16* Asrc = A + (size_t)(row0 + rowA) * 768 + cA;
  const u16* Bsrc = W + (size_t)(col0 + rowB) * 768 + cB;

  bf8 ra0 = *(const bf8*)(Asrc);
  bf8 ra1 = *(const bf8*)(Asrc + 32);
  bf8 rb0 = *(const bf8*)(Bsrc);
  bf8 rb1 = *(const bf8*)(Bsrc + 8);
  bf8 rb2 = *(const bf8*)(Bsrc + 16);
  bf8 rb3 = *(const bf8*)(Bsrc + 24);

  f4 acc[2][4];
#pragma unroll
  for (int i = 0; i < 2; ++i)
#pragma unroll
    for (int j = 0; j < 4; ++j) acc[i][j] = (f4){0.f, 0.f, 0.f, 0.f};

  for (int kt = 0; kt < 12; ++kt) {
    __syncthreads();
    *(bf8*)&a_lds[rowA][cA]      = ra0;
    *(bf8*)&a_lds[rowA][cA + 32] = ra1;
    *(bf8*)&b_lds[rowB][cB]      = rb0;
    *(bf8*)&b_lds[rowB][cB + 8]  = rb1;
    *(bf8*)&b_lds[rowB][cB + 16] = rb2;
    *(bf8*)&b_lds[rowB][cB + 24] = rb3;
    if (kt < 11) {
      const u16* as = Asrc + (kt + 1) * 64;
      const u16* bs = Bsrc + (kt + 1) * 64;
      ra0 = *(const bf8*)(as);
      ra1 = *(const bf8*)(as + 32);
      rb0 = *(const bf8*)(bs);
      rb1 = *(const bf8*)(bs + 8);
      rb2 = *(const bf8*)(bs + 16);
      rb3 = *(const bf8*)(bs + 24);
    }
    asm volatile("s_waitcnt lgkmcnt(0)" ::: "memory");
    __builtin_amdgcn_s_barrier();

#pragma unroll
    for (int kk = 0; kk < 2; ++kk) {
      bf8 a0 = *(const bf8*)&a_lds[wr * 32 + li][kk * 32 + g * 8];
      bf8 a1 = *(const bf8*)&a_lds[wr * 32 + 16 + li][kk * 32 + g * 8];
      bf8 b0 = *(const bf8*)&b_lds[wc * 64 + li][kk * 32 + g * 8];
      bf8 b1 = *(const bf8*)&b_lds[wc * 64 + 16 + li][kk * 32 + g * 8];
      bf8 b2 = *(const bf8*)&b_lds[wc * 64 + 32 + li][kk * 32 + g * 8];
      bf8 b3 = *(const bf8*)&b_lds[wc * 64 + 48 + li][kk * 32 + g * 8];
      acc[0][0] = MFMA_BF16(a0, b0, acc[0][0], 0, 0, 0);
      acc[0][1] = MFMA_BF16(a0, b1, acc[0][1], 0, 0, 0);
      acc[0][2] = MFMA_BF16(a0, b2, acc[0][2], 0, 0, 0);
      acc[0][3] = MFMA_BF16(a0, b3, acc[0][3], 0, 0, 0);
      acc[1][0] = MFMA_BF16(a1, b0, acc[1][0], 0, 0, 0);
      acc[1][1] = MFMA_BF16(a1, b1, acc[1][1], 0, 0, 0);
      acc[1][2] = MFMA_BF16(a1, b2, acc[1][2], 0, 0, 0);
      acc[1][3] = MFMA_BF16(a1, b3, acc[1][3], 0, 0, 0);
    }
  }

  const int wrow0 = row0 + wr * 32;
  const int wcol0 = col0 + wc * 64;

  if (EPI == 1 || EPI == 2) {
    float tmul = 1.0f;
    if (EPI == 2) tmul = temp[wcol0 >> 6] * LOG2E;   // fold temp AND log2e into Q
#pragma unroll
    for (int i = 0; i < 2; ++i)
#pragma unroll
      for (int r = 0; r < 4; ++r) {
        float ss = 0.f;
#pragma unroll
        for (int j = 0; j < 4; ++j) ss += acc[i][j][r] * acc[i][j][r];
#pragma unroll
        for (int msk = 1; msk < 16; msk <<= 1) ss += __shfl_xor(ss, msk, 64);
        float scl = tmul / fmaxf(sqrtf(ss), 1e-12f);
#pragma unroll
        for (int j = 0; j < 4; ++j) acc[i][j][r] *= scl;
      }
  }

#pragma unroll
  for (int i = 0; i < 2; ++i)
#pragma unroll
    for (int j = 0; j < 4; ++j)
#pragma unroll
      for (int r = 0; r < 4; ++r) {
        int row = wrow0 + i * 16 + g * 4 + r;
        int col = wcol0 + j * 16 + li;
        if (EPI == 3) Cf[(size_t)row * 768 + col] = acc[i][j][r];
        else          Cb[(size_t)row * 768 + col] = f2bf(acc[i][j][r]);
      }
}

// Fallback GEMM (W f32 inline-cvt, direct-from-global) for !stageW.
template <int EPI>
__global__ __launch_bounds__(256) void gemm_wf32(const u16* __restrict__ A,
                                                 const float* __restrict__ W,
                                                 u16* __restrict__ Cb,
                                                 float* __restrict__ Cf,
                                                 const float* __restrict__ temp)
{
  const int w  = threadIdx.x >> 6;
  const int ln = threadIdx.x & 63;
  const int li = ln & 15, g = ln >> 4;
  const int wr = w >> 1, wc = w & 1;
  const int row0 = blockIdx.x * 64 + wr * 32;
  const int col0 = blockIdx.y * 128 + wc * 64;

  const u16*   Ap = A + (size_t)(row0 + li) * 768 + g * 8;
  const float* Wp = W + (size_t)(col0 + li) * 768 + g * 8;

  f4 acc[2][4];
#pragma unroll
  for (int i = 0; i < 2; ++i)
#pragma unroll
    for (int j = 0; j < 4; ++j) acc[i][j] = (f4){0.f, 0.f, 0.f, 0.f};

  for (int k = 0; k < 768; k += 32) {
    bf8 a0 = *(const bf8*)(Ap + k);
    bf8 a1 = *(const bf8*)(Ap + (size_t)16 * 768 + k);
    bf8 b0 = ldcvt8(Wp + k);
    bf8 b1 = ldcvt8(Wp + (size_t)16 * 768 + k);
    bf8 b2 = ldcvt8(Wp + (size_t)32 * 768 + k);
    bf8 b3 = ldcvt8(Wp + (size_t)48 * 768 + k);
    acc[0][0] = MFMA_BF16(a0, b0, acc[0][0], 0, 0, 0);
    acc[0][1] = MFMA_BF16(a0, b1, acc[0][1], 0, 0, 0);
    acc[0][2] = MFMA_BF16(a0, b2, acc[0][2], 0, 0, 0);
    acc[0][3] = MFMA_BF16(a0, b3, acc[0][3], 0, 0, 0);
    acc[1][0] = MFMA_BF16(a1, b0, acc[1][0], 0, 0, 0);
    acc[1][1] = MFMA_BF16(a1, b1, acc[1][1], 0, 0, 0);
    acc[1][2] = MFMA_BF16(a1, b2, acc[1][2], 0, 0, 0);
    acc[1][3] = MFMA_BF16(a1, b3, acc[1][3], 0, 0, 0);
  }

  if (EPI == 1 || EPI == 2) {
    float tmul = 1.0f;
    if (EPI == 2) tmul = temp[col0 >> 6] * LOG2E;
#pragma unroll
    for (int i = 0; i < 2; ++i)
#pragma unroll
      for (int r = 0; r < 4; ++r) {
        float ss = 0.f;
#pragma unroll
        for (int j = 0; j < 4; ++j) ss += acc[i][j][r] * acc[i][j][r];
#pragma unroll
        for (int msk = 1; msk < 16; msk <<= 1) ss += __shfl_xor(ss, msk, 64);
        float scl = tmul / fmaxf(sqrtf(ss), 1e-12f);
#pragma unroll
        for (int j = 0; j < 4; ++j) acc[i][j][r] *= scl;
      }
  }

#pragma unroll
  for (int i = 0; i < 2; ++i)
#pragma unroll
    for (int j = 0; j < 4; ++j)
#pragma unroll
      for (int r = 0; r < 4; ++r) {
        int row = row0 + i * 16 + g * 4 + r;
        int col = col0 + j * 16 + li;
        if (EPI == 3) Cf[(size_t)row * 768 + col] = acc[i][j][r];
        else          Cb[(size_t)row * 768 + col] = f2bf(acc[i][j][r]);
      }
}

// Flash attention v6: QBLK=128 (wave owns 32 q-rows), fixed-shift exp2 softmax.
// Q pre-scaled by temp*log2e in GEMM epilogue; p = exp2(s - |temp|*log2e) exactly.
// Grid 768 = 48 bh x 16 q-tiles, XCD-chunked. K/V staged in LDS with T14 reg
// prefetch. O may alias Q (per-block exclusive rows, read-first).
__global__ __launch_bounds__(256, 3) void flash_attn(const u16* __restrict__ Q,
                                                     const u16* __restrict__ K,
                                                     const u16* __restrict__ V,
                                                     u16* __restrict__ O,
                                                     const float* __restrict__ temp)
{
  const int bid = blockIdx.x;
  const int vid = (bid & 7) * 96 + (bid >> 3);   // XCD-chunked remap (96 blocks/XCD)
  const int bh  = vid >> 4;                       // 6 bh per XCD
  const int qt  = 15 - (vid & 15);                // heavy tiles first
  const int b = bh / H_, h = bh % H_;
  const size_t base = (size_t)b * S_ * D_ + h * HD_;
  const u16* Qp = Q + base;
  const u16* Kp = K + base;
  const u16* Vp = V + base;
  u16*       Op = O + base;

  const float C2 = fabsf(temp[h]) * LOG2E;

  const int w  = threadIdx.x >> 6;
  const int ln = threadIdx.x & 63;
  const int li = ln & 15, g = ln >> 4;

  __shared__ __align__(16) u16 k_lds[64][72];
  __shared__ __align__(16) u16 vt[64][72];
  __shared__ __align__(16) u16 p_lds[4][32][72];

  const int q0 = qt * 128;

  bf8 qf[2][2];
#pragma unroll
  for (int i = 0; i < 2; ++i) {
    const u16* qp = Qp + (size_t)(q0 + w * 32 + i * 16 + li) * D_;
    qf[i][0] = *(const bf8*)(qp + g * 8);
    qf[i][1] = *(const bf8*)(qp + 32 + g * 8);
  }

  const int key2 = (threadIdx.x >> 3) * 2;
  const int d0   = (threadIdx.x & 7) * 8;
  const u16* ksrc = Kp + (size_t)key2 * D_ + d0;
  const u16* vsrc = Vp + (size_t)key2 * D_ + d0;

  bf8 ka = *(const bf8*)(ksrc);
  bf8 kb = *(const bf8*)(ksrc + D_);
  bf8 va = *(const bf8*)(vsrc);
  bf8 vb_ = *(const bf8*)(vsrc + D_);

  f4 o[2][4];
  float lp[2][4];
#pragma unroll
  for (int i = 0; i < 2; ++i)
#pragma unroll
    for (int c = 0; c < 4; ++c) { o[i][c] = (f4){0.f, 0.f, 0.f, 0.f}; lp[i][c] = 0.f; }

  const int nt = 2 * qt + 1;
  for (int kt = 0; kt <= nt; ++kt) {
    __syncthreads();
    {
      *(bf8*)&k_lds[key2][d0]     = ka;
      *(bf8*)&k_lds[key2 + 1][d0] = kb;
#pragma unroll
      for (int j = 0; j < 8; ++j) {
        ushort2 pr;
        pr.x = (u16)va[j]; pr.y = (u16)vb_[j];
        *(ushort2*)&vt[d0 + j][key2 ^ d0] = pr;
      }
    }
    if (kt < nt) {
      const u16* ks = ksrc + (size_t)(kt + 1) * 64 * D_;
      const u16* vs = vsrc + (size_t)(kt + 1) * 64 * D_;
      ka  = *(const bf8*)(ks);
      kb  = *(const bf8*)(ks + D_);
      va  = *(const bf8*)(vs);
      vb_ = *(const bf8*)(vs + D_);
    }
    asm volatile("s_waitcnt lgkmcnt(0)" ::: "memory");
    __builtin_amdgcn_s_barrier();

    // QK^T: 8 K-frag reads serve 16 MFMA
    f4 sc[2][4];
#pragma unroll
    for (int i = 0; i < 2; ++i)
#pragma unroll
      for (int c = 0; c < 4; ++c) sc[i][c] = (f4){0.f, 0.f, 0.f, 0.f};
#pragma unroll
    for (int c = 0; c < 4; ++c) {
      bf8 k0 = *(const bf8*)&k_lds[c * 16 + li][g * 8];
      bf8 k1 = *(const bf8*)&k_lds[c * 16 + li][32 + g * 8];
      sc[0][c] = MFMA_BF16(qf[0][0], k0, sc[0][c], 0, 0, 0);
      sc[0][c] = MFMA_BF16(qf[0][1], k1, sc[0][c], 0, 0, 0);
      sc[1][c] = MFMA_BF16(qf[1][0], k0, sc[1][c], 0, 0, 0);
      sc[1][c] = MFMA_BF16(qf[1][1], k1, sc[1][c], 0, 0, 0);
    }

    if (kt >= 2 * qt) {   // only the last two tiles touch the diagonal
#pragma unroll
      for (int i = 0; i < 2; ++i)
#pragma unroll
        for (int c = 0; c < 4; ++c)
#pragma unroll
          for (int r = 0; r < 4; ++r) {
            int col = kt * 64 + c * 16 + li;
            int row = q0 + w * 32 + i * 16 + g * 4 + r;
            if (col > row) sc[i][c][r] = -__builtin_inff();
          }
    }

    // fixed-shift exp2 softmax; in-lane partial row sums
#pragma unroll
    for (int i = 0; i < 2; ++i)
#pragma unroll
      for (int c = 0; c < 4; ++c)
#pragma unroll
        for (int r = 0; r < 4; ++r) {
          float p = exp2f(sc[i][c][r] - C2);
          sc[i][c][r] = p;
          lp[i][r] += p;
        }

    // P -> LDS (single-instruction cvt), XOR-swizzled
#pragma unroll
    for (int i = 0; i < 2; ++i)
#pragma unroll
      for (int c = 0; c < 4; ++c)
#pragma unroll
        for (int r = 0; r < 4; ++r)
          p_lds[w][i * 16 + g * 4 + r][(c * 16 + li) ^ (g << 3)] = cvt_bf16(sc[i][c][r]);

    // PV: 8 vt reads + 4 pa reads serve 16 MFMA
#pragma unroll
    for (int ks = 0; ks < 2; ++ks) {
      bf8 pa0 = *(const bf8*)&p_lds[w][li][(ks * 32 + g * 8) ^ ((li >> 2) << 3)];
      bf8 pa1 = *(const bf8*)&p_lds[w][16 + li][(ks * 32 + g * 8) ^ ((li >> 2) << 3)];
#pragma unroll
      for (int c = 0; c < 4; ++c) {
        int d  = c * 16 + li;
        int kbx = (ks * 32 + g * 8) ^ (d & 56);
        bf8 vv = *(const bf8*)&vt[d][kbx];
        o[0][c] = MFMA_BF16(pa0, vv, o[0][c], 0, 0, 0);
        o[1][c] = MFMA_BF16(pa1, vv, o[1][c], 0, 0, 0);
      }
    }
  }

  // epilogue: finish row sums, divide, store
#pragma unroll
  for (int i = 0; i < 2; ++i)
#pragma unroll
    for (int r = 0; r < 4; ++r) {
      float s = lp[i][r];
#pragma unroll
      for (int msk = 1; msk < 16; msk <<= 1) s += __shfl_xor(s, msk, 64);
      lp[i][r] = 1.0f / s;
    }
#pragma unroll
  for (int i = 0; i < 2; ++i)
#pragma unroll
    for (int c = 0; c < 4; ++c)
#pragma unroll
      for (int r = 0; r < 4; ++r) {
        int row = q0 + w * 32 + i * 16 + g * 4 + r;
        Op[(size_t)row * D_ + c * 16 + li] = cvt_bf16(o[i][c][r] * lp[i][r]);
      }
}

extern "C" void kernel_launch(void* const* d_in, const int* in_sizes, int n_in,
                              void* d_out, int out_size, void* d_ws, size_t ws_size,
                              hipStream_t stream) {
  const void *xv, *Wqv, *Wkv, *Wvv, *Wov, *tv;
  if (in_sizes[0] == M_ * D_) {
    xv = d_in[0]; Wqv = d_in[1]; Wkv = d_in[2]; Wvv = d_in[3]; Wov = d_in[4]; tv = d_in[5];
  } else {
    Wkv = d_in[0]; Wov = d_in[1]; Wqv = d_in[2]; Wvv = d_in[3]; tv = d_in[4]; xv = d_in[5];
  }
  const float* x    = (const float*)xv;
  const float* Wq   = (const float*)Wqv;
  const float* Wk   = (const float*)Wkv;
  const float* Wv   = (const float*)Wvv;
  const float* Wo   = (const float*)Wov;
  const float* temp = (const float*)tv;

  const size_t SZ  = (size_t)M_ * D_;   // 6291456
  const size_t WSZ = (size_t)D_ * D_;   // 589824
  u16* ws = (u16*)d_ws;
  u16* Qb = ws;
  u16* Kb = ws + SZ;
  u16* Vb = ws + 2 * SZ;
  u16* XB = (u16*)d_out;   // bf16(x) staged in d_out (scratch until final GEMM)

  const bool stageW = ws_size >= (3 * SZ + 4 * WSZ) * sizeof(u16);
  u16* Wqb = ws + 3 * SZ;
  u16* Wkb = Wqb + WSZ;
  u16* Wvb = Wkb + WSZ;
  u16* Wob = Wvb + WSZ;

  stage_cvt<<<2048, 256, 0, stream>>>(x, XB, (int)(SZ / 4));

  dim3 gg(M_ / 64, D_ / 128), bb(256);
  if (stageW) {
    stage_w4<<<dim3(192, 4), 256, 0, stream>>>(Wq, Wk, Wv, Wo, Wqb, Wkb, Wvb, Wob, (int)(WSZ / 4));
    gemm_v2<2><<<gg, bb, 0, stream>>>(XB, Wqb, Qb, nullptr, temp);
    gemm_v2<1><<<gg, bb, 0, stream>>>(XB, Wkb, Kb, nullptr, temp);
    gemm_v2<0><<<gg, bb, 0, stream>>>(XB, Wvb, Vb, nullptr, temp);
  } else {
    gemm_wf32<2><<<gg, bb, 0, stream>>>(XB, Wq, Qb, nullptr, temp);
    gemm_wf32<1><<<gg, bb, 0, stream>>>(XB, Wk, Kb, nullptr, temp);
    gemm_wf32<0><<<gg, bb, 0, stream>>>(XB, Wv, Vb, nullptr, temp);
  }

  // attention output overwrites Qb (safe: per-block exclusive rows)
  flash_attn<<<768, 256, 0, stream>>>(Qb, Kb, Vb, Qb, temp);

  if (stageW) gemm_v2<3><<<gg, bb, 0, stream>>>(Qb, Wob, nullptr, (float*)d_out, temp);
  else        gemm_wf32<3><<<gg, bb, 0, stream>>>(Qb, Wo, nullptr, (float*)d_out, temp);
}

// Round 16
// 160.347 us; speedup vs baseline: 1.1556x; 1.1556x over previous
//
#include <hip/hip_runtime.h>
#include <hip/hip_bf16.h>

#define B_ 4
#define S_ 2048
#define D_ 768
#define H_ 12
#define HD_ 64
#define M_ (B_*S_)   // 8192
#define LOG2E 1.44269504088896f

typedef __attribute__((ext_vector_type(8))) short bf8;
typedef __attribute__((ext_vector_type(4))) float f4;
typedef unsigned short u16;
typedef unsigned int   u32;

__device__ __forceinline__ float bf2f(u16 u) {
  union { u32 i; float f; } c; c.i = ((u32)u) << 16; return c.f;
}
__device__ __forceinline__ u16 f2bf(float x) {
  union { float f; u32 i; } c; c.f = x;
  u32 r = (c.i + 0x7FFFu + ((c.i >> 16) & 1u)) >> 16;
  return (u16)r;
}
// single-instruction RNE f32->bf16 (low half of v_cvt_pk result)
__device__ __forceinline__ u16 cvt_bf16(float x) {
  u32 r;
  asm("v_cvt_pk_bf16_f32 %0, %1, %1" : "=v"(r) : "v"(x));
  return (u16)r;
}

// f32 -> bf16 (rne), vectorized x4, grid-stride.
__global__ __launch_bounds__(256) void stage_cvt(const float* __restrict__ in,
                                                 u16* __restrict__ out, int n4)
{
  for (int i = blockIdx.x * blockDim.x + threadIdx.x; i < n4; i += gridDim.x * blockDim.x) {
    float4 v = ((const float4*)in)[i];
    ushort4 o;
    o.x = f2bf(v.x); o.y = f2bf(v.y); o.z = f2bf(v.z); o.w = f2bf(v.w);
    ((ushort4*)out)[i] = o;
  }
}

// 4 weight matrices in one launch (blockIdx.y selects).
__global__ __launch_bounds__(256) void stage_w4(const float* __restrict__ w0, const float* __restrict__ w1,
                                                const float* __restrict__ w2, const float* __restrict__ w3,
                                                u16* __restrict__ o0, u16* __restrict__ o1,
                                                u16* __restrict__ o2, u16* __restrict__ o3, int n4)
{
  const float* src = (blockIdx.y == 0) ? w0 : (blockIdx.y == 1) ? w1 : (blockIdx.y == 2) ? w2 : w3;
  u16*         dst = (blockIdx.y == 0) ? o0 : (blockIdx.y == 1) ? o1 : (blockIdx.y == 2) ? o2 : o3;
  for (int i = blockIdx.x * blockDim.x + threadIdx.x; i < n4; i += gridDim.x * blockDim.x) {
    float4 v = ((const float4*)src)[i];
    ushort4 o;
    o.x = f2bf(v.x); o.y = f2bf(v.y); o.z = f2bf(v.z); o.w = f2bf(v.w);
    ((ushort4*)dst)[i] = o;
  }
}

__device__ __forceinline__ bf8 ldcvt8(const float* __restrict__ p) {
  float4 a = *(const float4*)p;
  float4 b = *(const float4*)(p + 4);
  bf8 r;
  r[0] = f2bf(a.x); r[1] = f2bf(a.y); r[2] = f2bf(a.z); r[3] = f2bf(a.w);
  r[4] = f2bf(b.x); r[5] = f2bf(b.y); r[6] = f2bf(b.z); r[7] = f2bf(b.w);
  return r;
}

#define MFMA_BF16 __builtin_amdgcn_mfma_f32_16x16x32_bf16

// GEMM v2: LDS-staged + T14 reg prefetch, tile 64x128, BK=64.
// EPI: 0 = bf16 store; 1 = head-L2-normalize; 2 = normalize*temp[h]*log2e (Q path);
//      3 = f32 store.
template <int EPI>
__global__ __launch_bounds__(256) void gemm_v2(const u16* __restrict__ A,
                                               const u16* __restrict__ W,
                                               u16* __restrict__ Cb,
                                               float* __restrict__ Cf,
                                               const float* __restrict__ temp)
{
  const int w  = threadIdx.x >> 6;
  const int ln = threadIdx.x & 63;
  const int li = ln & 15, g = ln >> 4;
  const int wr = w >> 1, wc = w & 1;
  const int row0 = blockIdx.x * 64;
  const int col0 = blockIdx.y * 128;

  __shared__ __align__(16) u16 a_lds[64][72];
  __shared__ __align__(16) u16 b_lds[128][72];

  const int rowA = threadIdx.x >> 2;
  const int cA   = (threadIdx.x & 3) * 8;
  const int rowB = threadIdx.x >> 1;
  const int cB   = (threadIdx.x & 1) * 32;

  const u16* Asrc = A + (size_t)(row0 + rowA) * 768 + cA;
  const u16* Bsrc = W + (size_t)(col0 + rowB) * 768 + cB;

  bf8 ra0 = *(const bf8*)(Asrc);
  bf8 ra1 = *(const bf8*)(Asrc + 32);
  bf8 rb0 = *(const bf8*)(Bsrc);
  bf8 rb1 = *(const bf8*)(Bsrc + 8);
  bf8 rb2 = *(const bf8*)(Bsrc + 16);
  bf8 rb3 = *(const bf8*)(Bsrc + 24);

  f4 acc[2][4];
#pragma unroll
  for (int i = 0; i < 2; ++i)
#pragma unroll
    for (int j = 0; j < 4; ++j) acc[i][j] = (f4){0.f, 0.f, 0.f, 0.f};

  for (int kt = 0; kt < 12; ++kt) {
    __syncthreads();
    *(bf8*)&a_lds[rowA][cA]      = ra0;
    *(bf8*)&a_lds[rowA][cA + 32] = ra1;
    *(bf8*)&b_lds[rowB][cB]      = rb0;
    *(bf8*)&b_lds[rowB][cB + 8]  = rb1;
    *(bf8*)&b_lds[rowB][cB + 16] = rb2;
    *(bf8*)&b_lds[rowB][cB + 24] = rb3;
    if (kt < 11) {
      const u16* as = Asrc + (kt + 1) * 64;
      const u16* bs = Bsrc + (kt + 1) * 64;
      ra0 = *(const bf8*)(as);
      ra1 = *(const bf8*)(as + 32);
      rb0 = *(const bf8*)(bs);
      rb1 = *(const bf8*)(bs + 8);
      rb2 = *(const bf8*)(bs + 16);
      rb3 = *(const bf8*)(bs + 24);
    }
    asm volatile("s_waitcnt lgkmcnt(0)" ::: "memory");
    __builtin_amdgcn_s_barrier();

#pragma unroll
    for (int kk = 0; kk < 2; ++kk) {
      bf8 a0 = *(const bf8*)&a_lds[wr * 32 + li][kk * 32 + g * 8];
      bf8 a1 = *(const bf8*)&a_lds[wr * 32 + 16 + li][kk * 32 + g * 8];
      bf8 b0 = *(const bf8*)&b_lds[wc * 64 + li][kk * 32 + g * 8];
      bf8 b1 = *(const bf8*)&b_lds[wc * 64 + 16 + li][kk * 32 + g * 8];
      bf8 b2 = *(const bf8*)&b_lds[wc * 64 + 32 + li][kk * 32 + g * 8];
      bf8 b3 = *(const bf8*)&b_lds[wc * 64 + 48 + li][kk * 32 + g * 8];
      acc[0][0] = MFMA_BF16(a0, b0, acc[0][0], 0, 0, 0);
      acc[0][1] = MFMA_BF16(a0, b1, acc[0][1], 0, 0, 0);
      acc[0][2] = MFMA_BF16(a0, b2, acc[0][2], 0, 0, 0);
      acc[0][3] = MFMA_BF16(a0, b3, acc[0][3], 0, 0, 0);
      acc[1][0] = MFMA_BF16(a1, b0, acc[1][0], 0, 0, 0);
      acc[1][1] = MFMA_BF16(a1, b1, acc[1][1], 0, 0, 0);
      acc[1][2] = MFMA_BF16(a1, b2, acc[1][2], 0, 0, 0);
      acc[1][3] = MFMA_BF16(a1, b3, acc[1][3], 0, 0, 0);
    }
  }

  const int wrow0 = row0 + wr * 32;
  const int wcol0 = col0 + wc * 64;

  if (EPI == 1 || EPI == 2) {
    float tmul = 1.0f;
    if (EPI == 2) tmul = temp[wcol0 >> 6] * LOG2E;   // fold temp AND log2e into Q
#pragma unroll
    for (int i = 0; i < 2; ++i)
#pragma unroll
      for (int r = 0; r < 4; ++r) {
        float ss = 0.f;
#pragma unroll
        for (int j = 0; j < 4; ++j) ss += acc[i][j][r] * acc[i][j][r];
#pragma unroll
        for (int msk = 1; msk < 16; msk <<= 1) ss += __shfl_xor(ss, msk, 64);
        float scl = tmul / fmaxf(sqrtf(ss), 1e-12f);
#pragma unroll
        for (int j = 0; j < 4; ++j) acc[i][j][r] *= scl;
      }
  }

#pragma unroll
  for (int i = 0; i < 2; ++i)
#pragma unroll
    for (int j = 0; j < 4; ++j)
#pragma unroll
      for (int r = 0; r < 4; ++r) {
        int row = wrow0 + i * 16 + g * 4 + r;
        int col = wcol0 + j * 16 + li;
        if (EPI == 3) Cf[(size_t)row * 768 + col] = acc[i][j][r];
        else          Cb[(size_t)row * 768 + col] = f2bf(acc[i][j][r]);
      }
}

// Fallback GEMM (W f32 inline-cvt, direct-from-global) for !stageW.
template <int EPI>
__global__ __launch_bounds__(256) void gemm_wf32(const u16* __restrict__ A,
                                                 const float* __restrict__ W,
                                                 u16* __restrict__ Cb,
                                                 float* __restrict__ Cf,
                                                 const float* __restrict__ temp)
{
  const int w  = threadIdx.x >> 6;
  const int ln = threadIdx.x & 63;
  const int li = ln & 15, g = ln >> 4;
  const int wr = w >> 1, wc = w & 1;
  const int row0 = blockIdx.x * 64 + wr * 32;
  const int col0 = blockIdx.y * 128 + wc * 64;

  const u16*   Ap = A + (size_t)(row0 + li) * 768 + g * 8;
  const float* Wp = W + (size_t)(col0 + li) * 768 + g * 8;

  f4 acc[2][4];
#pragma unroll
  for (int i = 0; i < 2; ++i)
#pragma unroll
    for (int j = 0; j < 4; ++j) acc[i][j] = (f4){0.f, 0.f, 0.f, 0.f};

  for (int k = 0; k < 768; k += 32) {
    bf8 a0 = *(const bf8*)(Ap + k);
    bf8 a1 = *(const bf8*)(Ap + (size_t)16 * 768 + k);
    bf8 b0 = ldcvt8(Wp + k);
    bf8 b1 = ldcvt8(Wp + (size_t)16 * 768 + k);
    bf8 b2 = ldcvt8(Wp + (size_t)32 * 768 + k);
    bf8 b3 = ldcvt8(Wp + (size_t)48 * 768 + k);
    acc[0][0] = MFMA_BF16(a0, b0, acc[0][0], 0, 0, 0);
    acc[0][1] = MFMA_BF16(a0, b1, acc[0][1], 0, 0, 0);
    acc[0][2] = MFMA_BF16(a0, b2, acc[0][2], 0, 0, 0);
    acc[0][3] = MFMA_BF16(a0, b3, acc[0][3], 0, 0, 0);
    acc[1][0] = MFMA_BF16(a1, b0, acc[1][0], 0, 0, 0);
    acc[1][1] = MFMA_BF16(a1, b1, acc[1][1], 0, 0, 0);
    acc[1][2] = MFMA_BF16(a1, b2, acc[1][2], 0, 0, 0);
    acc[1][3] = MFMA_BF16(a1, b3, acc[1][3], 0, 0, 0);
  }

  if (EPI == 1 || EPI == 2) {
    float tmul = 1.0f;
    if (EPI == 2) tmul = temp[col0 >> 6] * LOG2E;
#pragma unroll
    for (int i = 0; i < 2; ++i)
#pragma unroll
      for (int r = 0; r < 4; ++r) {
        float ss = 0.f;
#pragma unroll
        for (int j = 0; j < 4; ++j) ss += acc[i][j][r] * acc[i][j][r];
#pragma unroll
        for (int msk = 1; msk < 16; msk <<= 1) ss += __shfl_xor(ss, msk, 64);
        float scl = tmul / fmaxf(sqrtf(ss), 1e-12f);
#pragma unroll
        for (int j = 0; j < 4; ++j) acc[i][j][r] *= scl;
      }
  }

#pragma unroll
  for (int i = 0; i < 2; ++i)
#pragma unroll
    for (int j = 0; j < 4; ++j)
#pragma unroll
      for (int r = 0; r < 4; ++r) {
        int row = row0 + i * 16 + g * 4 + r;
        int col = col0 + j * 16 + li;
        if (EPI == 3) Cf[(size_t)row * 768 + col] = acc[i][j][r];
        else          Cb[(size_t)row * 768 + col] = f2bf(acc[i][j][r]);
      }
}

// Flash attention v7: QBLK=64 (R14 structure, best measured) + exp2 fixed-shift
// softmax + single-instruction bf16 packs. Q pre-scaled by temp*log2e.
// Grid 1536 = 48 bh x 32 q-tiles, XCD-chunked. K/V staged in LDS, T14 reg prefetch.
// O may alias Q (per-block exclusive rows, read-first).
__global__ __launch_bounds__(256, 4) void flash_attn(const u16* __restrict__ Q,
                                                     const u16* __restrict__ K,
                                                     const u16* __restrict__ V,
                                                     u16* __restrict__ O,
                                                     const float* __restrict__ temp)
{
  const int bid = blockIdx.x;
  const int vid = (bid & 7) * 192 + (bid >> 3);
  const int bh  = vid >> 5;
  const int qt  = 31 - (vid & 31);
  const int b = bh / H_, h = bh % H_;
  const size_t base = (size_t)b * S_ * D_ + h * HD_;
  const u16* Qp = Q + base;
  const u16* Kp = K + base;
  const u16* Vp = V + base;
  u16*       Op = O + base;

  const float C2 = fabsf(temp[h]) * LOG2E;

  const int w  = threadIdx.x >> 6;
  const int ln = threadIdx.x & 63;
  const int li = ln & 15, g = ln >> 4;

  __shared__ __align__(16) u16 k_lds[64][72];
  __shared__ __align__(16) u16 vt[64][72];
  __shared__ __align__(16) u16 p_lds[4][16][72];

  const int q0 = qt * 64;
  const int qrow = q0 + w * 16 + li;

  bf8 qf0 = *(const bf8*)(Qp + (size_t)qrow * D_ + g * 8);
  bf8 qf1 = *(const bf8*)(Qp + (size_t)qrow * D_ + 32 + g * 8);

  const int key2 = (threadIdx.x >> 3) * 2;
  const int d0   = (threadIdx.x & 7) * 8;
  const u16* ksrc = Kp + (size_t)key2 * D_ + d0;
  const u16* vsrc = Vp + (size_t)key2 * D_ + d0;

  bf8 ka = *(const bf8*)(ksrc);
  bf8 kb = *(const bf8*)(ksrc + D_);
  bf8 va = *(const bf8*)(vsrc);
  bf8 vb_ = *(const bf8*)(vsrc + D_);

  f4 o[4];
  float lp[4] = {0.f, 0.f, 0.f, 0.f};   // in-lane partial softmax denominators
#pragma unroll
  for (int c = 0; c < 4; ++c) o[c] = (f4){0.f, 0.f, 0.f, 0.f};

  for (int kt = 0; kt <= qt; ++kt) {
    __syncthreads();
    {
      *(bf8*)&k_lds[key2][d0]     = ka;
      *(bf8*)&k_lds[key2 + 1][d0] = kb;
#pragma unroll
      for (int j = 0; j < 8; ++j) {
        ushort2 pr;
        pr.x = (u16)va[j]; pr.y = (u16)vb_[j];
        *(ushort2*)&vt[d0 + j][key2 ^ d0] = pr;
      }
    }
    if (kt < qt) {
      const u16* ks = ksrc + (size_t)(kt + 1) * 64 * D_;
      const u16* vs = vsrc + (size_t)(kt + 1) * 64 * D_;
      ka  = *(const bf8*)(ks);
      kb  = *(const bf8*)(ks + D_);
      va  = *(const bf8*)(vs);
      vb_ = *(const bf8*)(vs + D_);
    }
    asm volatile("s_waitcnt lgkmcnt(0)" ::: "memory");
    __builtin_amdgcn_s_barrier();

    f4 sc[4];
#pragma unroll
    for (int c = 0; c < 4; ++c) sc[c] = (f4){0.f, 0.f, 0.f, 0.f};
#pragma unroll
    for (int c = 0; c < 4; ++c) {
      bf8 k0 = *(const bf8*)&k_lds[c * 16 + li][g * 8];
      bf8 k1 = *(const bf8*)&k_lds[c * 16 + li][32 + g * 8];
      sc[c] = MFMA_BF16(qf0, k0, sc[c], 0, 0, 0);
      sc[c] = MFMA_BF16(qf1, k1, sc[c], 0, 0, 0);
    }

    if (kt == qt) {
#pragma unroll
      for (int c = 0; c < 4; ++c)
#pragma unroll
        for (int r = 0; r < 4; ++r) {
          int col = kt * 64 + c * 16 + li;
          int row = q0 + w * 16 + g * 4 + r;
          if (col > row) sc[c][r] = -__builtin_inff();
        }
    }

    // fixed-shift exp2 softmax; in-lane partial row sums
#pragma unroll
    for (int c = 0; c < 4; ++c)
#pragma unroll
      for (int r = 0; r < 4; ++r) {
        float p = exp2f(sc[c][r] - C2);
        sc[c][r] = p;
        lp[r] += p;
      }

    // P -> LDS (single-instruction cvt), XOR-swizzled
#pragma unroll
    for (int c = 0; c < 4; ++c)
#pragma unroll
      for (int r = 0; r < 4; ++r)
        p_lds[w][g * 4 + r][(c * 16 + li) ^ (g << 3)] = cvt_bf16(sc[c][r]);

    // PV
#pragma unroll
    for (int ks = 0; ks < 2; ++ks) {
      bf8 pa = *(const bf8*)&p_lds[w][li][(ks * 32 + g * 8) ^ ((li >> 2) << 3)];
#pragma unroll
      for (int c = 0; c < 4; ++c) {
        int d  = c * 16 + li;
        int kbx = (ks * 32 + g * 8) ^ (d & 56);
        bf8 vv = *(const bf8*)&vt[d][kbx];
        o[c] = MFMA_BF16(pa, vv, o[c], 0, 0, 0);
      }
    }
  }

  // epilogue: finish row sums (one shfl reduce), divide, store
  float l[4];
#pragma unroll
  for (int r = 0; r < 4; ++r) {
    float s = lp[r];
#pragma unroll
    for (int msk = 1; msk < 16; msk <<= 1) s += __shfl_xor(s, msk, 64);
    l[r] = 1.0f / s;
  }
#pragma unroll
  for (int c = 0; c < 4; ++c)
#pragma unroll
    for (int r = 0; r < 4; ++r) {
      int row = q0 + w * 16 + g * 4 + r;
      Op[(size_t)row * D_ + c * 16 + li] = cvt_bf16(o[c][r] * l[r]);
    }
}

extern "C" void kernel_launch(void* const* d_in, const int* in_sizes, int n_in,
                              void* d_out, int out_size, void* d_ws, size_t ws_size,
                              hipStream_t stream) {
  const void *xv, *Wqv, *Wkv, *Wvv, *Wov, *tv;
  if (in_sizes[0] == M_ * D_) {
    xv = d_in[0]; Wqv = d_in[1]; Wkv = d_in[2]; Wvv = d_in[3]; Wov = d_in[4]; tv = d_in[5];
  } else {
    Wkv = d_in[0]; Wov = d_in[1]; Wqv = d_in[2]; Wvv = d_in[3]; tv = d_in[4]; xv = d_in[5];
  }
  const float* x    = (const float*)xv;
  const float* Wq   = (const float*)Wqv;
  const float* Wk   = (const float*)Wkv;
  const float* Wv   = (const float*)Wvv;
  const float* Wo   = (const float*)Wov;
  const float* temp = (const float*)tv;

  const size_t SZ  = (size_t)M_ * D_;   // 6291456
  const size_t WSZ = (size_t)D_ * D_;   // 589824
  u16* ws = (u16*)d_ws;
  u16* Qb = ws;
  u16* Kb = ws + SZ;
  u16* Vb = ws + 2 * SZ;
  u16* XB = (u16*)d_out;   // bf16(x) staged in d_out (scratch until final GEMM)

  const bool stageW = ws_size >= (3 * SZ + 4 * WSZ) * sizeof(u16);
  u16* Wqb = ws + 3 * SZ;
  u16* Wkb = Wqb + WSZ;
  u16* Wvb = Wkb + WSZ;
  u16* Wob = Wvb + WSZ;

  stage_cvt<<<2048, 256, 0, stream>>>(x, XB, (int)(SZ / 4));

  dim3 gg(M_ / 64, D_ / 128), bb(256);
  if (stageW) {
    stage_w4<<<dim3(192, 4), 256, 0, stream>>>(Wq, Wk, Wv, Wo, Wqb, Wkb, Wvb, Wob, (int)(WSZ / 4));
    gemm_v2<2><<<gg, bb, 0, stream>>>(XB, Wqb, Qb, nullptr, temp);
    gemm_v2<1><<<gg, bb, 0, stream>>>(XB, Wkb, Kb, nullptr, temp);
    gemm_v2<0><<<gg, bb, 0, stream>>>(XB, Wvb, Vb, nullptr, temp);
  } else {
    gemm_wf32<2><<<gg, bb, 0, stream>>>(XB, Wq, Qb, nullptr, temp);
    gemm_wf32<1><<<gg, bb, 0, stream>>>(XB, Wk, Kb, nullptr, temp);
    gemm_wf32<0><<<gg, bb, 0, stream>>>(XB, Wv, Vb, nullptr, temp);
  }

  // attention output overwrites Qb (safe: per-block exclusive rows)
  flash_attn<<<1536, 256, 0, stream>>>(Qb, Kb, Vb, Qb, temp);

  if (stageW) gemm_v2<3><<<gg, bb, 0, stream>>>(Qb, Wob, nullptr, (float*)d_out, temp);
  else        gemm_wf32<3><<<gg, bb, 0, stream>>>(Qb, Wo, nullptr, (float*)d_out, temp);
}

// Round 17
// 154.150 us; speedup vs baseline: 1.2020x; 1.0402x over previous
//
#include <hip/hip_runtime.h>
#include <hip/hip_bf16.h>

#define B_ 4
#define S_ 2048
#define D_ 768
#define H_ 12
#define HD_ 64
#define M_ (B_*S_)   // 8192
#define LOG2E 1.44269504088896f

typedef __attribute__((ext_vector_type(8))) short bf8;
typedef __attribute__((ext_vector_type(4))) float f4;
typedef unsigned short u16;
typedef unsigned int   u32;

__device__ __forceinline__ float bf2f(u16 u) {
  union { u32 i; float f; } c; c.i = ((u32)u) << 16; return c.f;
}
__device__ __forceinline__ u16 f2bf(float x) {
  union { float f; u32 i; } c; c.f = x;
  u32 r = (c.i + 0x7FFFu + ((c.i >> 16) & 1u)) >> 16;
  return (u16)r;
}
// single-instruction RNE f32->bf16 (low half of v_cvt_pk result)
__device__ __forceinline__ u16 cvt_bf16(float x) {
  u32 r;
  asm("v_cvt_pk_bf16_f32 %0, %1, %1" : "=v"(r) : "v"(x));
  return (u16)r;
}
// raw v_exp_f32: computes 2^x, no libcall fixup (domain is pre-scaled by log2e)
__device__ __forceinline__ float exp2_raw(float x) {
  float r;
  asm("v_exp_f32 %0, %1" : "=v"(r) : "v"(x));
  return r;
}

// f32 -> bf16 (rne), vectorized x4, grid-stride.
__global__ __launch_bounds__(256) void stage_cvt(const float* __restrict__ in,
                                                 u16* __restrict__ out, int n4)
{
  for (int i = blockIdx.x * blockDim.x + threadIdx.x; i < n4; i += gridDim.x * blockDim.x) {
    float4 v = ((const float4*)in)[i];
    ushort4 o;
    o.x = f2bf(v.x); o.y = f2bf(v.y); o.z = f2bf(v.z); o.w = f2bf(v.w);
    ((ushort4*)out)[i] = o;
  }
}

// 4 weight matrices in one launch (blockIdx.y selects).
__global__ __launch_bounds__(256) void stage_w4(const float* __restrict__ w0, const float* __restrict__ w1,
                                                const float* __restrict__ w2, const float* __restrict__ w3,
                                                u16* __restrict__ o0, u16* __restrict__ o1,
                                                u16* __restrict__ o2, u16* __restrict__ o3, int n4)
{
  const float* src = (blockIdx.y == 0) ? w0 : (blockIdx.y == 1) ? w1 : (blockIdx.y == 2) ? w2 : w3;
  u16*         dst = (blockIdx.y == 0) ? o0 : (blockIdx.y == 1) ? o1 : (blockIdx.y == 2) ? o2 : o3;
  for (int i = blockIdx.x * blockDim.x + threadIdx.x; i < n4; i += gridDim.x * blockDim.x) {
    float4 v = ((const float4*)src)[i];
    ushort4 o;
    o.x = f2bf(v.x); o.y = f2bf(v.y); o.z = f2bf(v.z); o.w = f2bf(v.w);
    ((ushort4*)dst)[i] = o;
  }
}

__device__ __forceinline__ bf8 ldcvt8(const float* __restrict__ p) {
  float4 a = *(const float4*)p;
  float4 b = *(const float4*)(p + 4);
  bf8 r;
  r[0] = f2bf(a.x); r[1] = f2bf(a.y); r[2] = f2bf(a.z); r[3] = f2bf(a.w);
  r[4] = f2bf(b.x); r[5] = f2bf(b.y); r[6] = f2bf(b.z); r[7] = f2bf(b.w);
  return r;
}

#define MFMA_BF16 __builtin_amdgcn_mfma_f32_16x16x32_bf16

// GEMM v2: LDS-staged + T14 reg prefetch, tile 64x128, BK=64.
// EPI: 0 = bf16 store; 1 = head-L2-normalize; 2 = normalize*temp[h]*log2e (Q path);
//      3 = f32 store.
template <int EPI>
__global__ __launch_bounds__(256) void gemm_v2(const u16* __restrict__ A,
                                               const u16* __restrict__ W,
                                               u16* __restrict__ Cb,
                                               float* __restrict__ Cf,
                                               const float* __restrict__ temp)
{
  const int w  = threadIdx.x >> 6;
  const int ln = threadIdx.x & 63;
  const int li = ln & 15, g = ln >> 4;
  const int wr = w >> 1, wc = w & 1;
  const int row0 = blockIdx.x * 64;
  const int col0 = blockIdx.y * 128;

  __shared__ __align__(16) u16 a_lds[64][72];
  __shared__ __align__(16) u16 b_lds[128][72];

  const int rowA = threadIdx.x >> 2;
  const int cA   = (threadIdx.x & 3) * 8;
  const int rowB = threadIdx.x >> 1;
  const int cB   = (threadIdx.x & 1) * 32;

  const u16* Asrc = A + (size_t)(row0 + rowA) * 768 + cA;
  const u16* Bsrc = W + (size_t)(col0 + rowB) * 768 + cB;

  bf8 ra0 = *(const bf8*)(Asrc);
  bf8 ra1 = *(const bf8*)(Asrc + 32);
  bf8 rb0 = *(const bf8*)(Bsrc);
  bf8 rb1 = *(const bf8*)(Bsrc + 8);
  bf8 rb2 = *(const bf8*)(Bsrc + 16);
  bf8 rb3 = *(const bf8*)(Bsrc + 24);

  f4 acc[2][4];
#pragma unroll
  for (int i = 0; i < 2; ++i)
#pragma unroll
    for (int j = 0; j < 4; ++j) acc[i][j] = (f4){0.f, 0.f, 0.f, 0.f};

  for (int kt = 0; kt < 12; ++kt) {
    __syncthreads();
    *(bf8*)&a_lds[rowA][cA]      = ra0;
    *(bf8*)&a_lds[rowA][cA + 32] = ra1;
    *(bf8*)&b_lds[rowB][cB]      = rb0;
    *(bf8*)&b_lds[rowB][cB + 8]  = rb1;
    *(bf8*)&b_lds[rowB][cB + 16] = rb2;
    *(bf8*)&b_lds[rowB][cB + 24] = rb3;
    if (kt < 11) {
      const u16* as = Asrc + (kt + 1) * 64;
      const u16* bs = Bsrc + (kt + 1) * 64;
      ra0 = *(const bf8*)(as);
      ra1 = *(const bf8*)(as + 32);
      rb0 = *(const bf8*)(bs);
      rb1 = *(const bf8*)(bs + 8);
      rb2 = *(const bf8*)(bs + 16);
      rb3 = *(const bf8*)(bs + 24);
    }
    asm volatile("s_waitcnt lgkmcnt(0)" ::: "memory");
    __builtin_amdgcn_s_barrier();

#pragma unroll
    for (int kk = 0; kk < 2; ++kk) {
      bf8 a0 = *(const bf8*)&a_lds[wr * 32 + li][kk * 32 + g * 8];
      bf8 a1 = *(const bf8*)&a_lds[wr * 32 + 16 + li][kk * 32 + g * 8];
      bf8 b0 = *(const bf8*)&b_lds[wc * 64 + li][kk * 32 + g * 8];
      bf8 b1 = *(const bf8*)&b_lds[wc * 64 + 16 + li][kk * 32 + g * 8];
      bf8 b2 = *(const bf8*)&b_lds[wc * 64 + 32 + li][kk * 32 + g * 8];
      bf8 b3 = *(const bf8*)&b_lds[wc * 64 + 48 + li][kk * 32 + g * 8];
      acc[0][0] = MFMA_BF16(a0, b0, acc[0][0], 0, 0, 0);
      acc[0][1] = MFMA_BF16(a0, b1, acc[0][1], 0, 0, 0);
      acc[0][2] = MFMA_BF16(a0, b2, acc[0][2], 0, 0, 0);
      acc[0][3] = MFMA_BF16(a0, b3, acc[0][3], 0, 0, 0);
      acc[1][0] = MFMA_BF16(a1, b0, acc[1][0], 0, 0, 0);
      acc[1][1] = MFMA_BF16(a1, b1, acc[1][1], 0, 0, 0);
      acc[1][2] = MFMA_BF16(a1, b2, acc[1][2], 0, 0, 0);
      acc[1][3] = MFMA_BF16(a1, b3, acc[1][3], 0, 0, 0);
    }
  }

  const int wrow0 = row0 + wr * 32;
  const int wcol0 = col0 + wc * 64;

  if (EPI == 1 || EPI == 2) {
    float tmul = 1.0f;
    if (EPI == 2) tmul = temp[wcol0 >> 6] * LOG2E;   // fold temp AND log2e into Q
#pragma unroll
    for (int i = 0; i < 2; ++i)
#pragma unroll
      for (int r = 0; r < 4; ++r) {
        float ss = 0.f;
#pragma unroll
        for (int j = 0; j < 4; ++j) ss += acc[i][j][r] * acc[i][j][r];
#pragma unroll
        for (int msk = 1; msk < 16; msk <<= 1) ss += __shfl_xor(ss, msk, 64);
        float scl = tmul / fmaxf(sqrtf(ss), 1e-12f);
#pragma unroll
        for (int j = 0; j < 4; ++j) acc[i][j][r] *= scl;
      }
  }

#pragma unroll
  for (int i = 0; i < 2; ++i)
#pragma unroll
    for (int j = 0; j < 4; ++j)
#pragma unroll
      for (int r = 0; r < 4; ++r) {
        int row = wrow0 + i * 16 + g * 4 + r;
        int col = wcol0 + j * 16 + li;
        if (EPI == 3) Cf[(size_t)row * 768 + col] = acc[i][j][r];
        else          Cb[(size_t)row * 768 + col] = f2bf(acc[i][j][r]);
      }
}

// Fallback GEMM (W f32 inline-cvt, direct-from-global) for !stageW.
template <int EPI>
__global__ __launch_bounds__(256) void gemm_wf32(const u16* __restrict__ A,
                                                 const float* __restrict__ W,
                                                 u16* __restrict__ Cb,
                                                 float* __restrict__ Cf,
                                                 const float* __restrict__ temp)
{
  const int w  = threadIdx.x >> 6;
  const int ln = threadIdx.x & 63;
  const int li = ln & 15, g = ln >> 4;
  const int wr = w >> 1, wc = w & 1;
  const int row0 = blockIdx.x * 64 + wr * 32;
  const int col0 = blockIdx.y * 128 + wc * 64;

  const u16*   Ap = A + (size_t)(row0 + li) * 768 + g * 8;
  const float* Wp = W + (size_t)(col0 + li) * 768 + g * 8;

  f4 acc[2][4];
#pragma unroll
  for (int i = 0; i < 2; ++i)
#pragma unroll
    for (int j = 0; j < 4; ++j) acc[i][j] = (f4){0.f, 0.f, 0.f, 0.f};

  for (int k = 0; k < 768; k += 32) {
    bf8 a0 = *(const bf8*)(Ap + k);
    bf8 a1 = *(const bf8*)(Ap + (size_t)16 * 768 + k);
    bf8 b0 = ldcvt8(Wp + k);
    bf8 b1 = ldcvt8(Wp + (size_t)16 * 768 + k);
    bf8 b2 = ldcvt8(Wp + (size_t)32 * 768 + k);
    bf8 b3 = ldcvt8(Wp + (size_t)48 * 768 + k);
    acc[0][0] = MFMA_BF16(a0, b0, acc[0][0], 0, 0, 0);
    acc[0][1] = MFMA_BF16(a0, b1, acc[0][1], 0, 0, 0);
    acc[0][2] = MFMA_BF16(a0, b2, acc[0][2], 0, 0, 0);
    acc[0][3] = MFMA_BF16(a0, b3, acc[0][3], 0, 0, 0);
    acc[1][0] = MFMA_BF16(a1, b0, acc[1][0], 0, 0, 0);
    acc[1][1] = MFMA_BF16(a1, b1, acc[1][1], 0, 0, 0);
    acc[1][2] = MFMA_BF16(a1, b2, acc[1][2], 0, 0, 0);
    acc[1][3] = MFMA_BF16(a1, b3, acc[1][3], 0, 0, 0);
  }

  if (EPI == 1 || EPI == 2) {
    float tmul = 1.0f;
    if (EPI == 2) tmul = temp[col0 >> 6] * LOG2E;
#pragma unroll
    for (int i = 0; i < 2; ++i)
#pragma unroll
      for (int r = 0; r < 4; ++r) {
        float ss = 0.f;
#pragma unroll
        for (int j = 0; j < 4; ++j) ss += acc[i][j][r] * acc[i][j][r];
#pragma unroll
        for (int msk = 1; msk < 16; msk <<= 1) ss += __shfl_xor(ss, msk, 64);
        float scl = tmul / fmaxf(sqrtf(ss), 1e-12f);
#pragma unroll
        for (int j = 0; j < 4; ++j) acc[i][j][r] *= scl;
      }
  }

#pragma unroll
  for (int i = 0; i < 2; ++i)
#pragma unroll
    for (int j = 0; j < 4; ++j)
#pragma unroll
      for (int r = 0; r < 4; ++r) {
        int row = row0 + i * 16 + g * 4 + r;
        int col = col0 + j * 16 + li;
        if (EPI == 3) Cf[(size_t)row * 768 + col] = acc[i][j][r];
        else          Cb[(size_t)row * 768 + col] = f2bf(acc[i][j][r]);
      }
}

// Flash attention v8: QBLK=64, fixed-shift softmax via RAW v_exp_f32 (2^x),
// single-instruction bf16 packs. Q pre-scaled by temp*log2e in GEMM epilogue.
// Grid 1536 = 48 bh x 32 q-tiles, XCD-chunked. K/V staged in LDS, T14 reg prefetch.
// O may alias Q (per-block exclusive rows, read-first).
__global__ __launch_bounds__(256, 4) void flash_attn(const u16* __restrict__ Q,
                                                     const u16* __restrict__ K,
                                                     const u16* __restrict__ V,
                                                     u16* __restrict__ O,
                                                     const float* __restrict__ temp)
{
  const int bid = blockIdx.x;
  const int vid = (bid & 7) * 192 + (bid >> 3);
  const int bh  = vid >> 5;
  const int qt  = 31 - (vid & 31);
  const int b = bh / H_, h = bh % H_;
  const size_t base = (size_t)b * S_ * D_ + h * HD_;
  const u16* Qp = Q + base;
  const u16* Kp = K + base;
  const u16* Vp = V + base;
  u16*       Op = O + base;

  const float C2 = fabsf(temp[h]) * LOG2E;

  const int w  = threadIdx.x >> 6;
  const int ln = threadIdx.x & 63;
  const int li = ln & 15, g = ln >> 4;

  __shared__ __align__(16) u16 k_lds[64][72];
  __shared__ __align__(16) u16 vt[64][72];
  __shared__ __align__(16) u16 p_lds[4][16][72];

  const int q0 = qt * 64;
  const int qrow = q0 + w * 16 + li;

  bf8 qf0 = *(const bf8*)(Qp + (size_t)qrow * D_ + g * 8);
  bf8 qf1 = *(const bf8*)(Qp + (size_t)qrow * D_ + 32 + g * 8);

  const int key2 = (threadIdx.x >> 3) * 2;
  const int d0   = (threadIdx.x & 7) * 8;
  const u16* ksrc = Kp + (size_t)key2 * D_ + d0;
  const u16* vsrc = Vp + (size_t)key2 * D_ + d0;

  bf8 ka = *(const bf8*)(ksrc);
  bf8 kb = *(const bf8*)(ksrc + D_);
  bf8 va = *(const bf8*)(vsrc);
  bf8 vb_ = *(const bf8*)(vsrc + D_);

  f4 o[4];
  float lp[4] = {0.f, 0.f, 0.f, 0.f};   // in-lane partial softmax denominators
#pragma unroll
  for (int c = 0; c < 4; ++c) o[c] = (f4){0.f, 0.f, 0.f, 0.f};

  for (int kt = 0; kt <= qt; ++kt) {
    __syncthreads();
    {
      *(bf8*)&k_lds[key2][d0]     = ka;
      *(bf8*)&k_lds[key2 + 1][d0] = kb;
#pragma unroll
      for (int j = 0; j < 8; ++j) {
        ushort2 pr;
        pr.x = (u16)va[j]; pr.y = (u16)vb_[j];
        *(ushort2*)&vt[d0 + j][key2 ^ d0] = pr;
      }
    }
    if (kt < qt) {
      const u16* ks = ksrc + (size_t)(kt + 1) * 64 * D_;
      const u16* vs = vsrc + (size_t)(kt + 1) * 64 * D_;
      ka  = *(const bf8*)(ks);
      kb  = *(const bf8*)(ks + D_);
      va  = *(const bf8*)(vs);
      vb_ = *(const bf8*)(vs + D_);
    }
    asm volatile("s_waitcnt lgkmcnt(0)" ::: "memory");
    __builtin_amdgcn_s_barrier();

    f4 sc[4];
#pragma unroll
    for (int c = 0; c < 4; ++c) sc[c] = (f4){0.f, 0.f, 0.f, 0.f};
#pragma unroll
    for (int c = 0; c < 4; ++c) {
      bf8 k0 = *(const bf8*)&k_lds[c * 16 + li][g * 8];
      bf8 k1 = *(const bf8*)&k_lds[c * 16 + li][32 + g * 8];
      sc[c] = MFMA_BF16(qf0, k0, sc[c], 0, 0, 0);
      sc[c] = MFMA_BF16(qf1, k1, sc[c], 0, 0, 0);
    }

    if (kt == qt) {
#pragma unroll
      for (int c = 0; c < 4; ++c)
#pragma unroll
        for (int r = 0; r < 4; ++r) {
          int col = kt * 64 + c * 16 + li;
          int row = q0 + w * 16 + g * 4 + r;
          if (col > row) sc[c][r] = -__builtin_inff();
        }
    }

    // fixed-shift softmax via raw v_exp_f32 (2^x); in-lane partial row sums
#pragma unroll
    for (int c = 0; c < 4; ++c)
#pragma unroll
      for (int r = 0; r < 4; ++r) {
        float p = exp2_raw(sc[c][r] - C2);
        sc[c][r] = p;
        lp[r] += p;
      }

    // P -> LDS (single-instruction cvt), XOR-swizzled
#pragma unroll
    for (int c = 0; c < 4; ++c)
#pragma unroll
      for (int r = 0; r < 4; ++r)
        p_lds[w][g * 4 + r][(c * 16 + li) ^ (g << 3)] = cvt_bf16(sc[c][r]);

    // PV
#pragma unroll
    for (int ks = 0; ks < 2; ++ks) {
      bf8 pa = *(const bf8*)&p_lds[w][li][(ks * 32 + g * 8) ^ ((li >> 2) << 3)];
#pragma unroll
      for (int c = 0; c < 4; ++c) {
        int d  = c * 16 + li;
        int kbx = (ks * 32 + g * 8) ^ (d & 56);
        bf8 vv = *(const bf8*)&vt[d][kbx];
        o[c] = MFMA_BF16(pa, vv, o[c], 0, 0, 0);
      }
    }
  }

  // epilogue: finish row sums (one shfl reduce), divide, store
  float l[4];
#pragma unroll
  for (int r = 0; r < 4; ++r) {
    float s = lp[r];
#pragma unroll
    for (int msk = 1; msk < 16; msk <<= 1) s += __shfl_xor(s, msk, 64);
    l[r] = 1.0f / s;
  }
#pragma unroll
  for (int c = 0; c < 4; ++c)
#pragma unroll
    for (int r = 0; r < 4; ++r) {
      int row = q0 + w * 16 + g * 4 + r;
      Op[(size_t)row * D_ + c * 16 + li] = cvt_bf16(o[c][r] * l[r]);
    }
}

extern "C" void kernel_launch(void* const* d_in, const int* in_sizes, int n_in,
                              void* d_out, int out_size, void* d_ws, size_t ws_size,
                              hipStream_t stream) {
  const void *xv, *Wqv, *Wkv, *Wvv, *Wov, *tv;
  if (in_sizes[0] == M_ * D_) {
    xv = d_in[0]; Wqv = d_in[1]; Wkv = d_in[2]; Wvv = d_in[3]; Wov = d_in[4]; tv = d_in[5];
  } else {
    Wkv = d_in[0]; Wov = d_in[1]; Wqv = d_in[2]; Wvv = d_in[3]; tv = d_in[4]; xv = d_in[5];
  }
  const float* x    = (const float*)xv;
  const float* Wq   = (const float*)Wqv;
  const float* Wk   = (const float*)Wkv;
  const float* Wv   = (const float*)Wvv;
  const float* Wo   = (const float*)Wov;
  const float* temp = (const float*)tv;

  const size_t SZ  = (size_t)M_ * D_;   // 6291456
  const size_t WSZ = (size_t)D_ * D_;   // 589824
  u16* ws = (u16*)d_ws;
  u16* Qb = ws;
  u16* Kb = ws + SZ;
  u16* Vb = ws + 2 * SZ;
  u16* XB = (u16*)d_out;   // bf16(x) staged in d_out (scratch until final GEMM)

  const bool stageW = ws_size >= (3 * SZ + 4 * WSZ) * sizeof(u16);
  u16* Wqb = ws + 3 * SZ;
  u16* Wkb = Wqb + WSZ;
  u16* Wvb = Wkb + WSZ;
  u16* Wob = Wvb + WSZ;

  stage_cvt<<<2048, 256, 0, stream>>>(x, XB, (int)(SZ / 4));

  dim3 gg(M_ / 64, D_ / 128), bb(256);
  if (stageW) {
    stage_w4<<<dim3(192, 4), 256, 0, stream>>>(Wq, Wk, Wv, Wo, Wqb, Wkb, Wvb, Wob, (int)(WSZ / 4));
    gemm_v2<2><<<gg, bb, 0, stream>>>(XB, Wqb, Qb, nullptr, temp);
    gemm_v2<1><<<gg, bb, 0, stream>>>(XB, Wkb, Kb, nullptr, temp);
    gemm_v2<0><<<gg, bb, 0, stream>>>(XB, Wvb, Vb, nullptr, temp);
  } else {
    gemm_wf32<2><<<gg, bb, 0, stream>>>(XB, Wq, Qb, nullptr, temp);
    gemm_wf32<1><<<gg, bb, 0, stream>>>(XB, Wk, Kb, nullptr, temp);
    gemm_wf32<0><<<gg, bb, 0, stream>>>(XB, Wv, Vb, nullptr, temp);
  }

  // attention output overwrites Qb (safe: per-block exclusive rows)
  flash_attn<<<1536, 256, 0, stream>>>(Qb, Kb, Vb, Qb, temp);

  if (stageW) gemm_v2<3><<<gg, bb, 0, stream>>>(Qb, Wob, nullptr, (float*)d_out, temp);
  else        gemm_wf32<3><<<gg, bb, 0, stream>>>(Qb, Wo, nullptr, (float*)d_out, temp);
}

// Round 18
// 136.988 us; speedup vs baseline: 1.3526x; 1.1253x over previous
//
#include <hip/hip_runtime.h>
#include <hip/hip_bf16.h>

#define B_ 4
#define S_ 2048
#define D_ 768
#define H_ 12
#define HD_ 64
#define M_ (B_*S_)   // 8192
#define LOG2E 1.44269504088896f

typedef __attribute__((ext_vector_type(8))) short bf8;
typedef __attribute__((ext_vector_type(4))) float f4;
typedef unsigned short u16;
typedef unsigned int   u32;

typedef __attribute__((address_space(3))) u32 lds_u32;
typedef __attribute__((address_space(1))) const u32 glob_u32;

__device__ __forceinline__ float bf2f(u16 u) {
  union { u32 i; float f; } c; c.i = ((u32)u) << 16; return c.f;
}
__device__ __forceinline__ u16 f2bf(float x) {
  union { float f; u32 i; } c; c.f = x;
  u32 r = (c.i + 0x7FFFu + ((c.i >> 16) & 1u)) >> 16;
  return (u16)r;
}
__device__ __forceinline__ u16 cvt_bf16(float x) {
  u32 r;
  asm("v_cvt_pk_bf16_f32 %0, %1, %1" : "=v"(r) : "v"(x));
  return (u16)r;
}
__device__ __forceinline__ float exp2_raw(float x) {
  float r;
  asm("v_exp_f32 %0, %1" : "=v"(r) : "v"(x));
  return r;
}
// async global -> LDS, 16B per lane. l must be wave-uniform; HW adds lane*16.
__device__ __forceinline__ void glds16(const u16* g, u16* l) {
  __builtin_amdgcn_global_load_lds((glob_u32*)g, (lds_u32*)l, 16, 0, 0);
}

// Stage x + 4 weights f32 -> bf16 in ONE launch (blockIdx.y selects tensor).
__global__ __launch_bounds__(256) void stage_all(const float* __restrict__ x,
                                                 const float* __restrict__ w0, const float* __restrict__ w1,
                                                 const float* __restrict__ w2, const float* __restrict__ w3,
                                                 u16* __restrict__ xo,
                                                 u16* __restrict__ o0, u16* __restrict__ o1,
                                                 u16* __restrict__ o2, u16* __restrict__ o3,
                                                 int nx4, int nw4)
{
  int y = blockIdx.y;
  const float* src = (y == 0) ? x : (y == 1) ? w0 : (y == 2) ? w1 : (y == 3) ? w2 : w3;
  u16*         dst = (y == 0) ? xo : (y == 1) ? o0 : (y == 2) ? o1 : (y == 3) ? o2 : o3;
  int n4 = (y == 0) ? nx4 : nw4;
  for (int i = blockIdx.x * blockDim.x + threadIdx.x; i < n4; i += gridDim.x * blockDim.x) {
    float4 v = ((const float4*)src)[i];
    ushort4 o;
    o.x = f2bf(v.x); o.y = f2bf(v.y); o.z = f2bf(v.z); o.w = f2bf(v.w);
    ((ushort4*)dst)[i] = o;
  }
}

// f32 -> bf16 (fallback x staging)
__global__ __launch_bounds__(256) void stage_cvt(const float* __restrict__ in,
                                                 u16* __restrict__ out, int n4)
{
  for (int i = blockIdx.x * blockDim.x + threadIdx.x; i < n4; i += gridDim.x * blockDim.x) {
    float4 v = ((const float4*)in)[i];
    ushort4 o;
    o.x = f2bf(v.x); o.y = f2bf(v.y); o.z = f2bf(v.z); o.w = f2bf(v.w);
    ((ushort4*)out)[i] = o;
  }
}

__device__ __forceinline__ bf8 ldcvt8(const float* __restrict__ p) {
  float4 a = *(const float4*)p;
  float4 b = *(const float4*)(p + 4);
  bf8 r;
  r[0] = f2bf(a.x); r[1] = f2bf(a.y); r[2] = f2bf(a.z); r[3] = f2bf(a.w);
  r[4] = f2bf(b.x); r[5] = f2bf(b.y); r[6] = f2bf(b.z); r[7] = f2bf(b.w);
  return r;
}

#define MFMA_BF16 __builtin_amdgcn_mfma_f32_16x16x32_bf16

// GEMM v3 core: tile 64x128, BK=64, global_load_lds(16B) staging into LINEAR
// LDS with both-sides XOR chunk swizzle (chunk ^= row&7): staging lane fetches
// logical chunk (ln&7)^(ln>>3) (pre-swizzled source), readers XOR on read.
// Fragment reads land 2 lanes/bank = conflict-free.
// EPI: 0 = bf16; 1 = head-L2-norm; 2 = norm*temp[h]*log2e (Q); 3 = f32 store.
template <int EPI>
__device__ __forceinline__ void gemm_core(u16* a_lds, u16* b_lds,
                                          const u16* __restrict__ A,
                                          const u16* __restrict__ W,
                                          u16* __restrict__ Cb,
                                          float* __restrict__ Cf,
                                          const float* __restrict__ temp)
{
  const int w  = threadIdx.x >> 6;
  const int ln = threadIdx.x & 63;
  const int li = ln & 15, g = ln >> 4;
  const int wr = w >> 1, wc = w & 1;
  const int row0 = blockIdx.x * 64;
  const int col0 = blockIdx.y * 128;

  // staging source: lane covers row (seg*8 + srow), logical chunk (ln&7)^srow
  const int srow = ln >> 3;
  const int scol = ((ln & 7) ^ srow) * 8;
  const u16* Abase = A + (size_t)(row0 + srow) * 768 + scol;
  const u16* Bbase = W + (size_t)(col0 + srow) * 768 + scol;

  f4 acc[2][4];
#pragma unroll
  for (int i = 0; i < 2; ++i)
#pragma unroll
    for (int j = 0; j < 4; ++j) acc[i][j] = (f4){0.f, 0.f, 0.f, 0.f};

  for (int kt = 0; kt < 12; ++kt) {
    const int k0 = kt * 64;
    // A tile: 8 segments of 1KB (8 rows each); wave w stages segs 2w, 2w+1
#pragma unroll
    for (int i = 0; i < 2; ++i) {
      int seg = w * 2 + i;
      glds16(Abase + (size_t)(seg * 8) * 768 + k0, a_lds + seg * 512);
    }
    // B tile: 16 segments; wave w stages segs 4w..4w+3
#pragma unroll
    for (int i = 0; i < 4; ++i) {
      int seg = w * 4 + i;
      glds16(Bbase + (size_t)(seg * 8) * 768 + k0, b_lds + seg * 512);
    }
    asm volatile("s_waitcnt vmcnt(0)" ::: "memory");
    __syncthreads();

#pragma unroll
    for (int kk = 0; kk < 2; ++kk) {
      const int co = (((kk * 4 + g) ^ (li & 7)) * 8);   // swizzled chunk offset
      bf8 a0 = *(const bf8*)(a_lds + (wr * 32 + li) * 64 + co);
      bf8 a1 = *(const bf8*)(a_lds + (wr * 32 + 16 + li) * 64 + co);
      bf8 b0 = *(const bf8*)(b_lds + (wc * 64 + li) * 64 + co);
      bf8 b1 = *(const bf8*)(b_lds + (wc * 64 + 16 + li) * 64 + co);
      bf8 b2 = *(const bf8*)(b_lds + (wc * 64 + 32 + li) * 64 + co);
      bf8 b3 = *(const bf8*)(b_lds + (wc * 64 + 48 + li) * 64 + co);
      acc[0][0] = MFMA_BF16(a0, b0, acc[0][0], 0, 0, 0);
      acc[0][1] = MFMA_BF16(a0, b1, acc[0][1], 0, 0, 0);
      acc[0][2] = MFMA_BF16(a0, b2, acc[0][2], 0, 0, 0);
      acc[0][3] = MFMA_BF16(a0, b3, acc[0][3], 0, 0, 0);
      acc[1][0] = MFMA_BF16(a1, b0, acc[1][0], 0, 0, 0);
      acc[1][1] = MFMA_BF16(a1, b1, acc[1][1], 0, 0, 0);
      acc[1][2] = MFMA_BF16(a1, b2, acc[1][2], 0, 0, 0);
      acc[1][3] = MFMA_BF16(a1, b3, acc[1][3], 0, 0, 0);
    }
    __syncthreads();
  }

  const int wrow0 = row0 + wr * 32;
  const int wcol0 = col0 + wc * 64;

  if (EPI == 1 || EPI == 2) {
    float tmul = 1.0f;
    if (EPI == 2) tmul = temp[wcol0 >> 6] * LOG2E;
#pragma unroll
    for (int i = 0; i < 2; ++i)
#pragma unroll
      for (int r = 0; r < 4; ++r) {
        float ss = 0.f;
#pragma unroll
        for (int j = 0; j < 4; ++j) ss += acc[i][j][r] * acc[i][j][r];
#pragma unroll
        for (int msk = 1; msk < 16; msk <<= 1) ss += __shfl_xor(ss, msk, 64);
        float scl = tmul / fmaxf(sqrtf(ss), 1e-12f);
#pragma unroll
        for (int j = 0; j < 4; ++j) acc[i][j][r] *= scl;
      }
  }

#pragma unroll
  for (int i = 0; i < 2; ++i)
#pragma unroll
    for (int j = 0; j < 4; ++j)
#pragma unroll
      for (int r = 0; r < 4; ++r) {
        int row = wrow0 + i * 16 + g * 4 + r;
        int col = wcol0 + j * 16 + li;
        if (EPI == 3) Cf[(size_t)row * 768 + col] = acc[i][j][r];
        else          Cb[(size_t)row * 768 + col] = f2bf(acc[i][j][r]);
      }
}

// QKV in one launch: blockIdx.z selects matrix + epilogue.
__global__ __launch_bounds__(256) void gemm_qkv(const u16* __restrict__ XB,
                                                const u16* __restrict__ Wq, const u16* __restrict__ Wk,
                                                const u16* __restrict__ Wv,
                                                u16* __restrict__ Qb, u16* __restrict__ Kb,
                                                u16* __restrict__ Vb,
                                                const float* __restrict__ temp)
{
  __shared__ __align__(16) u16 a_lds[64 * 64];
  __shared__ __align__(16) u16 b_lds[128 * 64];
  if (blockIdx.z == 0)      gemm_core<2>(a_lds, b_lds, XB, Wq, Qb, nullptr, temp);
  else if (blockIdx.z == 1) gemm_core<1>(a_lds, b_lds, XB, Wk, Kb, nullptr, temp);
  else                      gemm_core<0>(a_lds, b_lds, XB, Wv, Vb, nullptr, temp);
}

__global__ __launch_bounds__(256) void gemm_out(const u16* __restrict__ A,
                                                const u16* __restrict__ W,
                                                float* __restrict__ Cf)
{
  __shared__ __align__(16) u16 a_lds[64 * 64];
  __shared__ __align__(16) u16 b_lds[128 * 64];
  gemm_core<3>(a_lds, b_lds, A, W, nullptr, Cf, nullptr);
}

// Fallback GEMM (W f32 inline-cvt, direct-from-global) for !stageW.
template <int EPI>
__global__ __launch_bounds__(256) void gemm_wf32(const u16* __restrict__ A,
                                                 const float* __restrict__ W,
                                                 u16* __restrict__ Cb,
                                                 float* __restrict__ Cf,
                                                 const float* __restrict__ temp)
{
  const int w  = threadIdx.x >> 6;
  const int ln = threadIdx.x & 63;
  const int li = ln & 15, g = ln >> 4;
  const int wr = w >> 1, wc = w & 1;
  const int row0 = blockIdx.x * 64 + wr * 32;
  const int col0 = blockIdx.y * 128 + wc * 64;

  const u16*   Ap = A + (size_t)(row0 + li) * 768 + g * 8;
  const float* Wp = W + (size_t)(col0 + li) * 768 + g * 8;

  f4 acc[2][4];
#pragma unroll
  for (int i = 0; i < 2; ++i)
#pragma unroll
    for (int j = 0; j < 4; ++j) acc[i][j] = (f4){0.f, 0.f, 0.f, 0.f};

  for (int k = 0; k < 768; k += 32) {
    bf8 a0 = *(const bf8*)(Ap + k);
    bf8 a1 = *(const bf8*)(Ap + (size_t)16 * 768 + k);
    bf8 b0 = ldcvt8(Wp + k);
    bf8 b1 = ldcvt8(Wp + (size_t)16 * 768 + k);
    bf8 b2 = ldcvt8(Wp + (size_t)32 * 768 + k);
    bf8 b3 = ldcvt8(Wp + (size_t)48 * 768 + k);
    acc[0][0] = MFMA_BF16(a0, b0, acc[0][0], 0, 0, 0);
    acc[0][1] = MFMA_BF16(a0, b1, acc[0][1], 0, 0, 0);
    acc[0][2] = MFMA_BF16(a0, b2, acc[0][2], 0, 0, 0);
    acc[0][3] = MFMA_BF16(a0, b3, acc[0][3], 0, 0, 0);
    acc[1][0] = MFMA_BF16(a1, b0, acc[1][0], 0, 0, 0);
    acc[1][1] = MFMA_BF16(a1, b1, acc[1][1], 0, 0, 0);
    acc[1][2] = MFMA_BF16(a1, b2, acc[1][2], 0, 0, 0);
    acc[1][3] = MFMA_BF16(a1, b3, acc[1][3], 0, 0, 0);
  }

  if (EPI == 1 || EPI == 2) {
    float tmul = 1.0f;
    if (EPI == 2) tmul = temp[col0 >> 6] * LOG2E;
#pragma unroll
    for (int i = 0; i < 2; ++i)
#pragma unroll
      for (int r = 0; r < 4; ++r) {
        float ss = 0.f;
#pragma unroll
        for (int j = 0; j < 4; ++j) ss += acc[i][j][r] * acc[i][j][r];
#pragma unroll
        for (int msk = 1; msk < 16; msk <<= 1) ss += __shfl_xor(ss, msk, 64);
        float scl = tmul / fmaxf(sqrtf(ss), 1e-12f);
#pragma unroll
        for (int j = 0; j < 4; ++j) acc[i][j][r] *= scl;
      }
  }

#pragma unroll
  for (int i = 0; i < 2; ++i)
#pragma unroll
    for (int j = 0; j < 4; ++j)
#pragma unroll
      for (int r = 0; r < 4; ++r) {
        int row = row0 + i * 16 + g * 4 + r;
        int col = col0 + j * 16 + li;
        if (EPI == 3) Cf[(size_t)row * 768 + col] = acc[i][j][r];
        else          Cb[(size_t)row * 768 + col] = f2bf(acc[i][j][r]);
      }
}

// Flash attention v8 (unchanged from R17, best measured): QBLK=64, fixed-shift
// softmax via raw v_exp_f32 (2^x), single-instruction bf16 packs.
__global__ __launch_bounds__(256, 4) void flash_attn(const u16* __restrict__ Q,
                                                     const u16* __restrict__ K,
                                                     const u16* __restrict__ V,
                                                     u16* __restrict__ O,
                                                     const float* __restrict__ temp)
{
  const int bid = blockIdx.x;
  const int vid = (bid & 7) * 192 + (bid >> 3);
  const int bh  = vid >> 5;
  const int qt  = 31 - (vid & 31);
  const int b = bh / H_, h = bh % H_;
  const size_t base = (size_t)b * S_ * D_ + h * HD_;
  const u16* Qp = Q + base;
  const u16* Kp = K + base;
  const u16* Vp = V + base;
  u16*       Op = O + base;

  const float C2 = fabsf(temp[h]) * LOG2E;

  const int w  = threadIdx.x >> 6;
  const int ln = threadIdx.x & 63;
  const int li = ln & 15, g = ln >> 4;

  __shared__ __align__(16) u16 k_lds[64][72];
  __shared__ __align__(16) u16 vt[64][72];
  __shared__ __align__(16) u16 p_lds[4][16][72];

  const int q0 = qt * 64;
  const int qrow = q0 + w * 16 + li;

  bf8 qf0 = *(const bf8*)(Qp + (size_t)qrow * D_ + g * 8);
  bf8 qf1 = *(const bf8*)(Qp + (size_t)qrow * D_ + 32 + g * 8);

  const int key2 = (threadIdx.x >> 3) * 2;
  const int d0   = (threadIdx.x & 7) * 8;
  const u16* ksrc = Kp + (size_t)key2 * D_ + d0;
  const u16* vsrc = Vp + (size_t)key2 * D_ + d0;

  bf8 ka = *(const bf8*)(ksrc);
  bf8 kb = *(const bf8*)(ksrc + D_);
  bf8 va = *(const bf8*)(vsrc);
  bf8 vb_ = *(const bf8*)(vsrc + D_);

  f4 o[4];
  float lp[4] = {0.f, 0.f, 0.f, 0.f};
#pragma unroll
  for (int c = 0; c < 4; ++c) o[c] = (f4){0.f, 0.f, 0.f, 0.f};

  for (int kt = 0; kt <= qt; ++kt) {
    __syncthreads();
    {
      *(bf8*)&k_lds[key2][d0]     = ka;
      *(bf8*)&k_lds[key2 + 1][d0] = kb;
#pragma unroll
      for (int j = 0; j < 8; ++j) {
        ushort2 pr;
        pr.x = (u16)va[j]; pr.y = (u16)vb_[j];
        *(ushort2*)&vt[d0 + j][key2 ^ d0] = pr;
      }
    }
    if (kt < qt) {
      const u16* ks = ksrc + (size_t)(kt + 1) * 64 * D_;
      const u16* vs = vsrc + (size_t)(kt + 1) * 64 * D_;
      ka  = *(const bf8*)(ks);
      kb  = *(const bf8*)(ks + D_);
      va  = *(const bf8*)(vs);
      vb_ = *(const bf8*)(vs + D_);
    }
    asm volatile("s_waitcnt lgkmcnt(0)" ::: "memory");
    __builtin_amdgcn_s_barrier();

    f4 sc[4];
#pragma unroll
    for (int c = 0; c < 4; ++c) sc[c] = (f4){0.f, 0.f, 0.f, 0.f};
#pragma unroll
    for (int c = 0; c < 4; ++c) {
      bf8 k0 = *(const bf8*)&k_lds[c * 16 + li][g * 8];
      bf8 k1 = *(const bf8*)&k_lds[c * 16 + li][32 + g * 8];
      sc[c] = MFMA_BF16(qf0, k0, sc[c], 0, 0, 0);
      sc[c] = MFMA_BF16(qf1, k1, sc[c], 0, 0, 0);
    }

    if (kt == qt) {
#pragma unroll
      for (int c = 0; c < 4; ++c)
#pragma unroll
        for (int r = 0; r < 4; ++r) {
          int col = kt * 64 + c * 16 + li;
          int row = q0 + w * 16 + g * 4 + r;
          if (col > row) sc[c][r] = -__builtin_inff();
        }
    }

#pragma unroll
    for (int c = 0; c < 4; ++c)
#pragma unroll
      for (int r = 0; r < 4; ++r) {
        float p = exp2_raw(sc[c][r] - C2);
        sc[c][r] = p;
        lp[r] += p;
      }

#pragma unroll
    for (int c = 0; c < 4; ++c)
#pragma unroll
      for (int r = 0; r < 4; ++r)
        p_lds[w][g * 4 + r][(c * 16 + li) ^ (g << 3)] = cvt_bf16(sc[c][r]);

#pragma unroll
    for (int ks = 0; ks < 2; ++ks) {
      bf8 pa = *(const bf8*)&p_lds[w][li][(ks * 32 + g * 8) ^ ((li >> 2) << 3)];
#pragma unroll
      for (int c = 0; c < 4; ++c) {
        int d  = c * 16 + li;
        int kbx = (ks * 32 + g * 8) ^ (d & 56);
        bf8 vv = *(const bf8*)&vt[d][kbx];
        o[c] = MFMA_BF16(pa, vv, o[c], 0, 0, 0);
      }
    }
  }

  float l[4];
#pragma unroll
  for (int r = 0; r < 4; ++r) {
    float s = lp[r];
#pragma unroll
    for (int msk = 1; msk < 16; msk <<= 1) s += __shfl_xor(s, msk, 64);
    l[r] = 1.0f / s;
  }
#pragma unroll
  for (int c = 0; c < 4; ++c)
#pragma unroll
    for (int r = 0; r < 4; ++r) {
      int row = q0 + w * 16 + g * 4 + r;
      Op[(size_t)row * D_ + c * 16 + li] = cvt_bf16(o[c][r] * l[r]);
    }
}

extern "C" void kernel_launch(void* const* d_in, const int* in_sizes, int n_in,
                              void* d_out, int out_size, void* d_ws, size_t ws_size,
                              hipStream_t stream) {
  const void *xv, *Wqv, *Wkv, *Wvv, *Wov, *tv;
  if (in_sizes[0] == M_ * D_) {
    xv = d_in[0]; Wqv = d_in[1]; Wkv = d_in[2]; Wvv = d_in[3]; Wov = d_in[4]; tv = d_in[5];
  } else {
    Wkv = d_in[0]; Wov = d_in[1]; Wqv = d_in[2]; Wvv = d_in[3]; tv = d_in[4]; xv = d_in[5];
  }
  const float* x    = (const float*)xv;
  const float* Wq   = (const float*)Wqv;
  const float* Wk   = (const float*)Wkv;
  const float* Wv   = (const float*)Wvv;
  const float* Wo   = (const float*)Wov;
  const float* temp = (const float*)tv;

  const size_t SZ  = (size_t)M_ * D_;   // 6291456
  const size_t WSZ = (size_t)D_ * D_;   // 589824
  u16* ws = (u16*)d_ws;
  u16* Qb = ws;
  u16* Kb = ws + SZ;
  u16* Vb = ws + 2 * SZ;
  u16* XB = (u16*)d_out;   // bf16(x) staged in d_out (scratch until final GEMM)

  const bool stageW = ws_size >= (3 * SZ + 4 * WSZ) * sizeof(u16);
  u16* Wqb = ws + 3 * SZ;
  u16* Wkb = Wqb + WSZ;
  u16* Wvb = Wkb + WSZ;
  u16* Wob = Wvb + WSZ;

  if (stageW) {
    stage_all<<<dim3(512, 5), 256, 0, stream>>>(x, Wq, Wk, Wv, Wo,
                                                XB, Wqb, Wkb, Wvb, Wob,
                                                (int)(SZ / 4), (int)(WSZ / 4));
    gemm_qkv<<<dim3(M_ / 64, D_ / 128, 3), 256, 0, stream>>>(XB, Wqb, Wkb, Wvb,
                                                             Qb, Kb, Vb, temp);
    flash_attn<<<1536, 256, 0, stream>>>(Qb, Kb, Vb, Qb, temp);
    gemm_out<<<dim3(M_ / 64, D_ / 128), 256, 0, stream>>>(Qb, Wob, (float*)d_out);
  } else {
    dim3 gg(M_ / 64, D_ / 128), bb(256);
    stage_cvt<<<2048, 256, 0, stream>>>(x, XB, (int)(SZ / 4));
    gemm_wf32<2><<<gg, bb, 0, stream>>>(XB, Wq, Qb, nullptr, temp);
    gemm_wf32<1><<<gg, bb, 0, stream>>>(XB, Wk, Kb, nullptr, temp);
    gemm_wf32<0><<<gg, bb, 0, stream>>>(XB, Wv, Vb, nullptr, temp);
    flash_attn<<<1536, 256, 0, stream>>>(Qb, Kb, Vb, Qb, temp);
    gemm_wf32<3><<<gg, bb, 0, stream>>>(Qb, Wo, nullptr, (float*)d_out, temp);
  }
}

// Round 19
// 127.119 us; speedup vs baseline: 1.4576x; 1.0776x over previous
//
#include <hip/hip_runtime.h>
#include <hip/hip_bf16.h>

#define B_ 4
#define S_ 2048
#define D_ 768
#define H_ 12
#define HD_ 64
#define M_ (B_*S_)   // 8192
#define LOG2E 1.44269504088896f

typedef __attribute__((ext_vector_type(8))) short bf8;
typedef __attribute__((ext_vector_type(4))) float f4;
typedef unsigned short u16;
typedef unsigned int   u32;

typedef __attribute__((address_space(3))) u32 lds_u32;
typedef __attribute__((address_space(1))) const u32 glob_u32;

__device__ __forceinline__ float bf2f(u16 u) {
  union { u32 i; float f; } c; c.i = ((u32)u) << 16; return c.f;
}
__device__ __forceinline__ u16 f2bf(float x) {
  union { float f; u32 i; } c; c.f = x;
  u32 r = (c.i + 0x7FFFu + ((c.i >> 16) & 1u)) >> 16;
  return (u16)r;
}
__device__ __forceinline__ u16 cvt_bf16(float x) {
  u32 r;
  asm("v_cvt_pk_bf16_f32 %0, %1, %1" : "=v"(r) : "v"(x));
  return (u16)r;
}
__device__ __forceinline__ float exp2_raw(float x) {
  float r;
  asm("v_exp_f32 %0, %1" : "=v"(r) : "v"(x));
  return r;
}
__device__ __forceinline__ void glds16(const u16* g, u16* l) {
  __builtin_amdgcn_global_load_lds((glob_u32*)g, (lds_u32*)l, 16, 0, 0);
}

// Stage x + 4 weights f32 -> bf16 in ONE launch (blockIdx.y selects tensor).
__global__ __launch_bounds__(256) void stage_all(const float* __restrict__ x,
                                                 const float* __restrict__ w0, const float* __restrict__ w1,
                                                 const float* __restrict__ w2, const float* __restrict__ w3,
                                                 u16* __restrict__ xo,
                                                 u16* __restrict__ o0, u16* __restrict__ o1,
                                                 u16* __restrict__ o2, u16* __restrict__ o3,
                                                 int nx4, int nw4)
{
  int y = blockIdx.y;
  const float* src = (y == 0) ? x : (y == 1) ? w0 : (y == 2) ? w1 : (y == 3) ? w2 : w3;
  u16*         dst = (y == 0) ? xo : (y == 1) ? o0 : (y == 2) ? o1 : (y == 3) ? o2 : o3;
  int n4 = (y == 0) ? nx4 : nw4;
  for (int i = blockIdx.x * blockDim.x + threadIdx.x; i < n4; i += gridDim.x * blockDim.x) {
    float4 v = ((const float4*)src)[i];
    ushort4 o;
    o.x = f2bf(v.x); o.y = f2bf(v.y); o.z = f2bf(v.z); o.w = f2bf(v.w);
    ((ushort4*)dst)[i] = o;
  }
}

// f32 -> bf16 (fallback x staging)
__global__ __launch_bounds__(256) void stage_cvt(const float* __restrict__ in,
                                                 u16* __restrict__ out, int n4)
{
  for (int i = blockIdx.x * blockDim.x + threadIdx.x; i < n4; i += gridDim.x * blockDim.x) {
    float4 v = ((const float4*)in)[i];
    ushort4 o;
    o.x = f2bf(v.x); o.y = f2bf(v.y); o.z = f2bf(v.z); o.w = f2bf(v.w);
    ((ushort4*)out)[i] = o;
  }
}

__device__ __forceinline__ bf8 ldcvt8(const float* __restrict__ p) {
  float4 a = *(const float4*)p;
  float4 b = *(const float4*)(p + 4);
  bf8 r;
  r[0] = f2bf(a.x); r[1] = f2bf(a.y); r[2] = f2bf(a.z); r[3] = f2bf(a.w);
  r[4] = f2bf(b.x); r[5] = f2bf(b.y); r[6] = f2bf(b.z); r[7] = f2bf(b.w);
  return r;
}

#define MFMA_BF16 __builtin_amdgcn_mfma_f32_16x16x32_bf16

// GEMM v3 core (R18 structure, row0/col0 passed in for XCD-sliced dispatch):
// tile 64x128, BK=64, global_load_lds(16B) into linear LDS w/ both-sides XOR
// chunk swizzle. EPI: 0 bf16; 1 head-L2-norm; 2 norm*temp[h]*log2e; 3 f32.
template <int EPI>
__device__ __forceinline__ void gemm_core(u16* a_lds, u16* b_lds,
                                          int row0, int col0,
                                          const u16* __restrict__ A,
                                          const u16* __restrict__ W,
                                          u16* __restrict__ Cb,
                                          float* __restrict__ Cf,
                                          const float* __restrict__ temp)
{
  const int w  = threadIdx.x >> 6;
  const int ln = threadIdx.x & 63;
  const int li = ln & 15, g = ln >> 4;
  const int wr = w >> 1, wc = w & 1;

  const int srow = ln >> 3;
  const int scol = ((ln & 7) ^ srow) * 8;
  const u16* Abase = A + (size_t)(row0 + srow) * 768 + scol;
  const u16* Bbase = W + (size_t)(col0 + srow) * 768 + scol;

  f4 acc[2][4];
#pragma unroll
  for (int i = 0; i < 2; ++i)
#pragma unroll
    for (int j = 0; j < 4; ++j) acc[i][j] = (f4){0.f, 0.f, 0.f, 0.f};

  for (int kt = 0; kt < 12; ++kt) {
    const int k0 = kt * 64;
#pragma unroll
    for (int i = 0; i < 2; ++i) {
      int seg = w * 2 + i;
      glds16(Abase + (size_t)(seg * 8) * 768 + k0, a_lds + seg * 512);
    }
#pragma unroll
    for (int i = 0; i < 4; ++i) {
      int seg = w * 4 + i;
      glds16(Bbase + (size_t)(seg * 8) * 768 + k0, b_lds + seg * 512);
    }
    asm volatile("s_waitcnt vmcnt(0)" ::: "memory");
    __syncthreads();

#pragma unroll
    for (int kk = 0; kk < 2; ++kk) {
      const int co = (((kk * 4 + g) ^ (li & 7)) * 8);
      bf8 a0 = *(const bf8*)(a_lds + (wr * 32 + li) * 64 + co);
      bf8 a1 = *(const bf8*)(a_lds + (wr * 32 + 16 + li) * 64 + co);
      bf8 b0 = *(const bf8*)(b_lds + (wc * 64 + li) * 64 + co);
      bf8 b1 = *(const bf8*)(b_lds + (wc * 64 + 16 + li) * 64 + co);
      bf8 b2 = *(const bf8*)(b_lds + (wc * 64 + 32 + li) * 64 + co);
      bf8 b3 = *(const bf8*)(b_lds + (wc * 64 + 48 + li) * 64 + co);
      acc[0][0] = MFMA_BF16(a0, b0, acc[0][0], 0, 0, 0);
      acc[0][1] = MFMA_BF16(a0, b1, acc[0][1], 0, 0, 0);
      acc[0][2] = MFMA_BF16(a0, b2, acc[0][2], 0, 0, 0);
      acc[0][3] = MFMA_BF16(a0, b3, acc[0][3], 0, 0, 0);
      acc[1][0] = MFMA_BF16(a1, b0, acc[1][0], 0, 0, 0);
      acc[1][1] = MFMA_BF16(a1, b1, acc[1][1], 0, 0, 0);
      acc[1][2] = MFMA_BF16(a1, b2, acc[1][2], 0, 0, 0);
      acc[1][3] = MFMA_BF16(a1, b3, acc[1][3], 0, 0, 0);
    }
    __syncthreads();
  }

  const int wrow0 = row0 + wr * 32;
  const int wcol0 = col0 + wc * 64;

  if (EPI == 1 || EPI == 2) {
    float tmul = 1.0f;
    if (EPI == 2) tmul = temp[wcol0 >> 6] * LOG2E;
#pragma unroll
    for (int i = 0; i < 2; ++i)
#pragma unroll
      for (int r = 0; r < 4; ++r) {
        float ss = 0.f;
#pragma unroll
        for (int j = 0; j < 4; ++j) ss += acc[i][j][r] * acc[i][j][r];
#pragma unroll
        for (int msk = 1; msk < 16; msk <<= 1) ss += __shfl_xor(ss, msk, 64);
        float scl = tmul / fmaxf(sqrtf(ss), 1e-12f);
#pragma unroll
        for (int j = 0; j < 4; ++j) acc[i][j][r] *= scl;
      }
  }

#pragma unroll
  for (int i = 0; i < 2; ++i)
#pragma unroll
    for (int j = 0; j < 4; ++j)
#pragma unroll
      for (int r = 0; r < 4; ++r) {
        int row = wrow0 + i * 16 + g * 4 + r;
        int col = wcol0 + j * 16 + li;
        if (EPI == 3) Cf[(size_t)row * 768 + col] = acc[i][j][r];
        else          Cb[(size_t)row * 768 + col] = f2bf(acc[i][j][r]);
      }
}

// QKV: 1D grid 2304, XCD row-slice remap — each XCD owns 16 row-blocks (1.57MB
// A slice, L2-resident) x all (z, col).
__global__ __launch_bounds__(256) void gemm_qkv(const u16* __restrict__ XB,
                                                const u16* __restrict__ Wq, const u16* __restrict__ Wk,
                                                const u16* __restrict__ Wv,
                                                u16* __restrict__ Qb, u16* __restrict__ Kb,
                                                u16* __restrict__ Vb,
                                                const float* __restrict__ temp)
{
  __shared__ __align__(16) u16 a_lds[64 * 64];
  __shared__ __align__(16) u16 b_lds[128 * 64];
  const int bid  = blockIdx.x;
  const int xcd  = bid & 7;
  const int j    = bid >> 3;          // 0..287
  const int row0 = (xcd * 16 + j / 18) * 64;
  const int rest = j % 18;
  const int z    = rest / 6;
  const int col0 = (rest % 6) * 128;
  if (z == 0)      gemm_core<2>(a_lds, b_lds, row0, col0, XB, Wq, Qb, nullptr, temp);
  else if (z == 1) gemm_core<1>(a_lds, b_lds, row0, col0, XB, Wk, Kb, nullptr, temp);
  else             gemm_core<0>(a_lds, b_lds, row0, col0, XB, Wv, Vb, nullptr, temp);
}

// Output GEMM: 1D grid 768, XCD row-slice remap.
__global__ __launch_bounds__(256) void gemm_out(const u16* __restrict__ A,
                                                const u16* __restrict__ W,
                                                float* __restrict__ Cf)
{
  __shared__ __align__(16) u16 a_lds[64 * 64];
  __shared__ __align__(16) u16 b_lds[128 * 64];
  const int bid  = blockIdx.x;
  const int xcd  = bid & 7;
  const int j    = bid >> 3;          // 0..95
  const int row0 = (xcd * 16 + j / 6) * 64;
  const int col0 = (j % 6) * 128;
  gemm_core<3>(a_lds, b_lds, row0, col0, A, W, nullptr, Cf, nullptr);
}

// Fallback GEMM (W f32 inline-cvt, direct-from-global) for !stageW.
template <int EPI>
__global__ __launch_bounds__(256) void gemm_wf32(const u16* __restrict__ A,
                                                 const float* __restrict__ W,
                                                 u16* __restrict__ Cb,
                                                 float* __restrict__ Cf,
                                                 const float* __restrict__ temp)
{
  const int w  = threadIdx.x >> 6;
  const int ln = threadIdx.x & 63;
  const int li = ln & 15, g = ln >> 4;
  const int wr = w >> 1, wc = w & 1;
  const int row0 = blockIdx.x * 64 + wr * 32;
  const int col0 = blockIdx.y * 128 + wc * 64;

  const u16*   Ap = A + (size_t)(row0 + li) * 768 + g * 8;
  const float* Wp = W + (size_t)(col0 + li) * 768 + g * 8;

  f4 acc[2][4];
#pragma unroll
  for (int i = 0; i < 2; ++i)
#pragma unroll
    for (int j = 0; j < 4; ++j) acc[i][j] = (f4){0.f, 0.f, 0.f, 0.f};

  for (int k = 0; k < 768; k += 32) {
    bf8 a0 = *(const bf8*)(Ap + k);
    bf8 a1 = *(const bf8*)(Ap + (size_t)16 * 768 + k);
    bf8 b0 = ldcvt8(Wp + k);
    bf8 b1 = ldcvt8(Wp + (size_t)16 * 768 + k);
    bf8 b2 = ldcvt8(Wp + (size_t)32 * 768 + k);
    bf8 b3 = ldcvt8(Wp + (size_t)48 * 768 + k);
    acc[0][0] = MFMA_BF16(a0, b0, acc[0][0], 0, 0, 0);
    acc[0][1] = MFMA_BF16(a0, b1, acc[0][1], 0, 0, 0);
    acc[0][2] = MFMA_BF16(a0, b2, acc[0][2], 0, 0, 0);
    acc[0][3] = MFMA_BF16(a0, b3, acc[0][3], 0, 0, 0);
    acc[1][0] = MFMA_BF16(a1, b0, acc[1][0], 0, 0, 0);
    acc[1][1] = MFMA_BF16(a1, b1, acc[1][1], 0, 0, 0);
    acc[1][2] = MFMA_BF16(a1, b2, acc[1][2], 0, 0, 0);
    acc[1][3] = MFMA_BF16(a1, b3, acc[1][3], 0, 0, 0);
  }

  if (EPI == 1 || EPI == 2) {
    float tmul = 1.0f;
    if (EPI == 2) tmul = temp[col0 >> 6] * LOG2E;
#pragma unroll
    for (int i = 0; i < 2; ++i)
#pragma unroll
      for (int r = 0; r < 4; ++r) {
        float ss = 0.f;
#pragma unroll
        for (int j = 0; j < 4; ++j) ss += acc[i][j][r] * acc[i][j][r];
#pragma unroll
        for (int msk = 1; msk < 16; msk <<= 1) ss += __shfl_xor(ss, msk, 64);
        float scl = tmul / fmaxf(sqrtf(ss), 1e-12f);
#pragma unroll
        for (int j = 0; j < 4; ++j) acc[i][j][r] *= scl;
      }
  }

#pragma unroll
  for (int i = 0; i < 2; ++i)
#pragma unroll
    for (int j = 0; j < 4; ++j)
#pragma unroll
      for (int r = 0; r < 4; ++r) {
        int row = row0 + i * 16 + g * 4 + r;
        int col = col0 + j * 16 + li;
        if (EPI == 3) Cf[(size_t)row * 768 + col] = acc[i][j][r];
        else          Cb[(size_t)row * 768 + col] = f2bf(acc[i][j][r]);
      }
}

// Flash attention v9: inner loop identical to v8; dispatch order is now LPT
// (globally heavy-first per XCD): qt = 31 - j/6 descending across all 6 bh.
__global__ __launch_bounds__(256, 4) void flash_attn(const u16* __restrict__ Q,
                                                     const u16* __restrict__ K,
                                                     const u16* __restrict__ V,
                                                     u16* __restrict__ O,
                                                     const float* __restrict__ temp)
{
  const int bid = blockIdx.x;
  const int xcd = bid & 7;
  const int j   = bid >> 3;           // 0..191
  const int bh  = xcd * 6 + j % 6;    // 6 bh per XCD (K/V L2-resident)
  const int qt  = 31 - j / 6;         // LPT: heaviest first, globally
  const int b = bh / H_, h = bh % H_;
  const size_t base = (size_t)b * S_ * D_ + h * HD_;
  const u16* Qp = Q + base;
  const u16* Kp = K + base;
  const u16* Vp = V + base;
  u16*       Op = O + base;

  const float C2 = fabsf(temp[h]) * LOG2E;

  const int w  = threadIdx.x >> 6;
  const int ln = threadIdx.x & 63;
  const int li = ln & 15, g = ln >> 4;

  __shared__ __align__(16) u16 k_lds[64][72];
  __shared__ __align__(16) u16 vt[64][72];
  __shared__ __align__(16) u16 p_lds[4][16][72];

  const int q0 = qt * 64;
  const int qrow = q0 + w * 16 + li;

  bf8 qf0 = *(const bf8*)(Qp + (size_t)qrow * D_ + g * 8);
  bf8 qf1 = *(const bf8*)(Qp + (size_t)qrow * D_ + 32 + g * 8);

  const int key2 = (threadIdx.x >> 3) * 2;
  const int d0   = (threadIdx.x & 7) * 8;
  const u16* ksrc = Kp + (size_t)key2 * D_ + d0;
  const u16* vsrc = Vp + (size_t)key2 * D_ + d0;

  bf8 ka = *(const bf8*)(ksrc);
  bf8 kb = *(const bf8*)(ksrc + D_);
  bf8 va = *(const bf8*)(vsrc);
  bf8 vb_ = *(const bf8*)(vsrc + D_);

  f4 o[4];
  float lp[4] = {0.f, 0.f, 0.f, 0.f};
#pragma unroll
  for (int c = 0; c < 4; ++c) o[c] = (f4){0.f, 0.f, 0.f, 0.f};

  for (int kt = 0; kt <= qt; ++kt) {
    __syncthreads();
    {
      *(bf8*)&k_lds[key2][d0]     = ka;
      *(bf8*)&k_lds[key2 + 1][d0] = kb;
#pragma unroll
      for (int j2 = 0; j2 < 8; ++j2) {
        ushort2 pr;
        pr.x = (u16)va[j2]; pr.y = (u16)vb_[j2];
        *(ushort2*)&vt[d0 + j2][key2 ^ d0] = pr;
      }
    }
    if (kt < qt) {
      const u16* ks = ksrc + (size_t)(kt + 1) * 64 * D_;
      const u16* vs = vsrc + (size_t)(kt + 1) * 64 * D_;
      ka  = *(const bf8*)(ks);
      kb  = *(const bf8*)(ks + D_);
      va  = *(const bf8*)(vs);
      vb_ = *(const bf8*)(vs + D_);
    }
    asm volatile("s_waitcnt lgkmcnt(0)" ::: "memory");
    __builtin_amdgcn_s_barrier();

    f4 sc[4];
#pragma unroll
    for (int c = 0; c < 4; ++c) sc[c] = (f4){0.f, 0.f, 0.f, 0.f};
#pragma unroll
    for (int c = 0; c < 4; ++c) {
      bf8 k0 = *(const bf8*)&k_lds[c * 16 + li][g * 8];
      bf8 k1 = *(const bf8*)&k_lds[c * 16 + li][32 + g * 8];
      sc[c] = MFMA_BF16(qf0, k0, sc[c], 0, 0, 0);
      sc[c] = MFMA_BF16(qf1, k1, sc[c], 0, 0, 0);
    }

    if (kt == qt) {
#pragma unroll
      for (int c = 0; c < 4; ++c)
#pragma unroll
        for (int r = 0; r < 4; ++r) {
          int col = kt * 64 + c * 16 + li;
          int row = q0 + w * 16 + g * 4 + r;
          if (col > row) sc[c][r] = -__builtin_inff();
        }
    }

#pragma unroll
    for (int c = 0; c < 4; ++c)
#pragma unroll
      for (int r = 0; r < 4; ++r) {
        float p = exp2_raw(sc[c][r] - C2);
        sc[c][r] = p;
        lp[r] += p;
      }

#pragma unroll
    for (int c = 0; c < 4; ++c)
#pragma unroll
      for (int r = 0; r < 4; ++r)
        p_lds[w][g * 4 + r][(c * 16 + li) ^ (g << 3)] = cvt_bf16(sc[c][r]);

#pragma unroll
    for (int ks = 0; ks < 2; ++ks) {
      bf8 pa = *(const bf8*)&p_lds[w][li][(ks * 32 + g * 8) ^ ((li >> 2) << 3)];
#pragma unroll
      for (int c = 0; c < 4; ++c) {
        int d  = c * 16 + li;
        int kbx = (ks * 32 + g * 8) ^ (d & 56);
        bf8 vv = *(const bf8*)&vt[d][kbx];
        o[c] = MFMA_BF16(pa, vv, o[c], 0, 0, 0);
      }
    }
  }

  float l[4];
#pragma unroll
  for (int r = 0; r < 4; ++r) {
    float s = lp[r];
#pragma unroll
    for (int msk = 1; msk < 16; msk <<= 1) s += __shfl_xor(s, msk, 64);
    l[r] = 1.0f / s;
  }
#pragma unroll
  for (int c = 0; c < 4; ++c)
#pragma unroll
    for (int r = 0; r < 4; ++r) {
      int row = q0 + w * 16 + g * 4 + r;
      Op[(size_t)row * D_ + c * 16 + li] = cvt_bf16(o[c][r] * l[r]);
    }
}

extern "C" void kernel_launch(void* const* d_in, const int* in_sizes, int n_in,
                              void* d_out, int out_size, void* d_ws, size_t ws_size,
                              hipStream_t stream) {
  const void *xv, *Wqv, *Wkv, *Wvv, *Wov, *tv;
  if (in_sizes[0] == M_ * D_) {
    xv = d_in[0]; Wqv = d_in[1]; Wkv = d_in[2]; Wvv = d_in[3]; Wov = d_in[4]; tv = d_in[5];
  } else {
    Wkv = d_in[0]; Wov = d_in[1]; Wqv = d_in[2]; Wvv = d_in[3]; tv = d_in[4]; xv = d_in[5];
  }
  const float* x    = (const float*)xv;
  const float* Wq   = (const float*)Wqv;
  const float* Wk   = (const float*)Wkv;
  const float* Wv   = (const float*)Wvv;
  const float* Wo   = (const float*)Wov;
  const float* temp = (const float*)tv;

  const size_t SZ  = (size_t)M_ * D_;   // 6291456
  const size_t WSZ = (size_t)D_ * D_;   // 589824
  u16* ws = (u16*)d_ws;
  u16* Qb = ws;
  u16* Kb = ws + SZ;
  u16* Vb = ws + 2 * SZ;
  u16* XB = (u16*)d_out;   // bf16(x) staged in d_out (scratch until final GEMM)

  const bool stageW = ws_size >= (3 * SZ + 4 * WSZ) * sizeof(u16);
  u16* Wqb = ws + 3 * SZ;
  u16* Wkb = Wqb + WSZ;
  u16* Wvb = Wkb + WSZ;
  u16* Wob = Wvb + WSZ;

  if (stageW) {
    stage_all<<<dim3(512, 5), 256, 0, stream>>>(x, Wq, Wk, Wv, Wo,
                                                XB, Wqb, Wkb, Wvb, Wob,
                                                (int)(SZ / 4), (int)(WSZ / 4));
    gemm_qkv<<<2304, 256, 0, stream>>>(XB, Wqb, Wkb, Wvb, Qb, Kb, Vb, temp);
    flash_attn<<<1536, 256, 0, stream>>>(Qb, Kb, Vb, Qb, temp);
    gemm_out<<<768, 256, 0, stream>>>(Qb, Wob, (float*)d_out);
  } else {
    dim3 gg(M_ / 64, D_ / 128), bb(256);
    stage_cvt<<<2048, 256, 0, stream>>>(x, XB, (int)(SZ / 4));
    gemm_wf32<2><<<gg, bb, 0, stream>>>(XB, Wq, Qb, nullptr, temp);
    gemm_wf32<1><<<gg, bb, 0, stream>>>(XB, Wk, Kb, nullptr, temp);
    gemm_wf32<0><<<gg, bb, 0, stream>>>(XB, Wv, Vb, nullptr, temp);
    flash_attn<<<1536, 256, 0, stream>>>(Qb, Kb, Vb, Qb, temp);
    gemm_wf32<3><<<gg, bb, 0, stream>>>(Qb, Wo, nullptr, (float*)d_out, temp);
  }
}